// Round 1
// baseline (1824.443 us; speedup 1.0000x reference)
//
#include <hip/hip_runtime.h>
#include <hip/hip_bf16.h>
#include <math.h>

// Problem constants (fixed by the reference)
#define BB   2
#define SS   2048
#define HIDD 1024
#define NHH  4
#define ROWS (BB*SS)      // 4096

__device__ __forceinline__ float waveReduceSum(float v) {
#pragma unroll
    for (int m = 1; m < 64; m <<= 1) v += __shfl_xor(v, m, 64);
    return v;
}

// ---------------- GEMM f32: C[M,N] = A[M,K] @ B[K,N], all row-major -------
// 64x64 tile, 256 threads, each thread 4x4, K-tile 16.
__global__ __launch_bounds__(256) void gemm_f32(const float* __restrict__ A,
                                                const float* __restrict__ B,
                                                float* __restrict__ C,
                                                int M, int N, int K) {
    __shared__ float As[16][64];   // [kk][m]
    __shared__ float Bs[16][64];   // [kk][n]
    const int t = threadIdx.x;
    const int rowBase = blockIdx.y * 64;
    const int colBase = blockIdx.x * 64;
    const int ty = t >> 4;             // 0..15
    const int tx = t & 15;             // 0..15

    float acc[4][4];
#pragma unroll
    for (int i = 0; i < 4; ++i)
#pragma unroll
        for (int j = 0; j < 4; ++j) acc[i][j] = 0.f;

    const int am = t >> 2;             // 0..63   (A row within tile)
    const int ak = (t & 3) << 2;       // 0,4,8,12 (A k within tile)
    const int bk = t >> 4;             // 0..15   (B k within tile)
    const int bn = (t & 15) << 2;      // 0..60   (B col within tile)

    for (int k0 = 0; k0 < K; k0 += 16) {
        float4 a4 = *(const float4*)&A[(size_t)(rowBase + am) * K + k0 + ak];
        float4 b4 = *(const float4*)&B[(size_t)(k0 + bk) * N + colBase + bn];
        As[ak + 0][am] = a4.x;
        As[ak + 1][am] = a4.y;
        As[ak + 2][am] = a4.z;
        As[ak + 3][am] = a4.w;
        *(float4*)&Bs[bk][bn] = b4;
        __syncthreads();
#pragma unroll
        for (int kk = 0; kk < 16; ++kk) {
            float4 av = *(const float4*)&As[kk][ty << 2];
            float4 bv = *(const float4*)&Bs[kk][tx << 2];
            float aa[4] = {av.x, av.y, av.z, av.w};
            float bb[4] = {bv.x, bv.y, bv.z, bv.w};
#pragma unroll
            for (int i = 0; i < 4; ++i)
#pragma unroll
                for (int j = 0; j < 4; ++j) acc[i][j] += aa[i] * bb[j];
        }
        __syncthreads();
    }
#pragma unroll
    for (int i = 0; i < 4; ++i) {
        float4 o = make_float4(acc[i][0], acc[i][1], acc[i][2], acc[i][3]);
        *(float4*)&C[(size_t)(rowBase + ty * 4 + i) * N + colBase + tx * 4] = o;
    }
}

// ---------------- beta = sigmoid(X @ Wb), Wb[1024][4] ----------------------
// One wave per row; lane covers 16 k's.
__global__ __launch_bounds__(256) void beta_kernel(const float* __restrict__ X,
                                                   const float* __restrict__ Wb,
                                                   float* __restrict__ beta) {
    const int gw   = (blockIdx.x * blockDim.x + threadIdx.x) >> 6;  // row
    const int lane = threadIdx.x & 63;
    if (gw >= ROWS) return;
    const float* x = X + (size_t)gw * HIDD;
    float a0 = 0.f, a1 = 0.f, a2 = 0.f, a3 = 0.f;
#pragma unroll
    for (int i = 0; i < 4; ++i) {
        const int k = lane * 16 + i * 4;
        float4 xv = *(const float4*)&x[k];
        float4 w0 = *(const float4*)&Wb[(size_t)(k + 0) * 4];
        float4 w1 = *(const float4*)&Wb[(size_t)(k + 1) * 4];
        float4 w2 = *(const float4*)&Wb[(size_t)(k + 2) * 4];
        float4 w3 = *(const float4*)&Wb[(size_t)(k + 3) * 4];
        a0 += xv.x * w0.x + xv.y * w1.x + xv.z * w2.x + xv.w * w3.x;
        a1 += xv.x * w0.y + xv.y * w1.y + xv.z * w2.y + xv.w * w3.y;
        a2 += xv.x * w0.z + xv.y * w1.z + xv.z * w2.z + xv.w * w3.z;
        a3 += xv.x * w0.w + xv.y * w1.w + xv.z * w2.w + xv.w * w3.w;
    }
    a0 = waveReduceSum(a0);
    a1 = waveReduceSum(a1);
    a2 = waveReduceSum(a2);
    a3 = waveReduceSum(a3);
    if (lane == 0) {
        float4 o = make_float4(1.f / (1.f + expf(-a0)), 1.f / (1.f + expf(-a1)),
                               1.f / (1.f + expf(-a2)), 1.f / (1.f + expf(-a3)));
        *(float4*)&beta[(size_t)gw * 4] = o;
    }
}

// ------- causal depthwise conv (K=4) + silu (+ optional per-head l2norm) ---
// One wave per (row, head); lane handles 4 channels.
__global__ __launch_bounds__(256) void conv_silu_kernel(const float* __restrict__ in,
                                                        const float* __restrict__ w,
                                                        float* __restrict__ out,
                                                        int doL2) {
    const int gw   = (blockIdx.x * blockDim.x + threadIdx.x) >> 6;
    const int lane = threadIdx.x & 63;
    const int r = gw >> 2;          // 0..4095  (b*S + s)
    const int h = gw & 3;
    const int b = r >> 11;
    const int s = r & 2047;
    const int c4 = h * 256 + lane * 4;

    const float4 wr0 = *(const float4*)&w[(size_t)(c4 + 0) * 4];
    const float4 wr1 = *(const float4*)&w[(size_t)(c4 + 1) * 4];
    const float4 wr2 = *(const float4*)&w[(size_t)(c4 + 2) * 4];
    const float4 wr3 = *(const float4*)&w[(size_t)(c4 + 3) * 4];

    const size_t rowB = (size_t)(b << 11);
    float4 x0 = make_float4(0,0,0,0), x1 = x0, x2 = x0, x3;
    if (s >= 3) x0 = *(const float4*)&in[(rowB + s - 3) * HIDD + c4];
    if (s >= 2) x1 = *(const float4*)&in[(rowB + s - 2) * HIDD + c4];
    if (s >= 1) x2 = *(const float4*)&in[(rowB + s - 1) * HIDD + c4];
    x3 = *(const float4*)&in[(rowB + s) * HIDD + c4];

    float y0 = wr0.x * x0.x + wr0.y * x1.x + wr0.z * x2.x + wr0.w * x3.x;
    float y1 = wr1.x * x0.y + wr1.y * x1.y + wr1.z * x2.y + wr1.w * x3.y;
    float y2 = wr2.x * x0.z + wr2.y * x1.z + wr2.z * x2.z + wr2.w * x3.z;
    float y3 = wr3.x * x0.w + wr3.y * x1.w + wr3.z * x2.w + wr3.w * x3.w;

    // silu
    y0 = y0 / (1.f + expf(-y0));
    y1 = y1 / (1.f + expf(-y1));
    y2 = y2 / (1.f + expf(-y2));
    y3 = y3 / (1.f + expf(-y3));

    if (doL2) {
        float ss = y0 * y0 + y1 * y1 + y2 * y2 + y3 * y3;
        ss = waveReduceSum(ss);
        float sc = rsqrtf(ss + 1e-6f);
        y0 *= sc; y1 *= sc; y2 *= sc; y3 *= sc;
    }
    *(float4*)&out[(size_t)r * HIDD + c4] = make_float4(y0, y1, y2, y3);
}

// ---------------- delta-rule scan: one wave per (b,h,column v) -------------
// lane owns 4 k-rows of S[:,v] in registers. 2048 sequential steps.
__global__ __launch_bounds__(256) void delta_kernel(const float* __restrict__ qc,
                                                    const float* __restrict__ kc,
                                                    const float* __restrict__ vc,
                                                    const float* __restrict__ beta,
                                                    float* __restrict__ o) {
    const int wav  = threadIdx.x >> 6;                 // 0..3
    const int lane = threadIdx.x & 63;
    const int bh   = blockIdx.x >> 6;                  // 0..7
    const int col  = ((blockIdx.x & 63) << 2) + wav;   // 0..255
    const int b = bh >> 2, h = bh & 3;

    const float* kb = kc + ((size_t)b * SS) * HIDD + h * 256;
    const float* qb = qc + ((size_t)b * SS) * HIDD + h * 256;
    const float* vb = vc + ((size_t)b * SS) * HIDD + h * 256 + col;
    const float* bb = beta + ((size_t)b * SS) * 4 + h;
    float* ob       = o  + ((size_t)b * SS) * HIDD + h * 256 + col;

    float S0 = 0.f, S1 = 0.f, S2 = 0.f, S3 = 0.f;

    float4 kv = *(const float4*)&kb[lane * 4];
    float4 qv = *(const float4*)&qb[lane * 4];
    float vt  = vb[0];
    float bt  = bb[0];

    for (int t = 0; t < SS; ++t) {
        float4 kn = make_float4(0,0,0,0), qn = kn;
        float vn = 0.f, bn = 0.f;
        if (t + 1 < SS) {
            kn = *(const float4*)&kb[(size_t)(t + 1) * HIDD + lane * 4];
            qn = *(const float4*)&qb[(size_t)(t + 1) * HIDD + lane * 4];
            vn = vb[(size_t)(t + 1) * HIDD];
            bn = bb[(size_t)(t + 1) * 4];
        }
        // kS[col]
        float part = kv.x * S0 + kv.y * S1 + kv.z * S2 + kv.w * S3;
        part = waveReduceSum(part);
        const float u = bt * (vt - part);
        S0 += kv.x * u; S1 += kv.y * u; S2 += kv.z * u; S3 += kv.w * u;
        // o[col] = q^T S (after update)
        float op = qv.x * S0 + qv.y * S1 + qv.z * S2 + qv.w * S3;
        op = waveReduceSum(op);
        if (lane == 0) ob[(size_t)t * HIDD] = op;

        kv = kn; qv = qn; vt = vn; bt = bn;
    }
}

// ---------------- rms_norm over last dim (256) with weight -----------------
__global__ __launch_bounds__(256) void rms_kernel(const float* __restrict__ in,
                                                  const float* __restrict__ w,
                                                  float* __restrict__ out) {
    const int gw   = (blockIdx.x * blockDim.x + threadIdx.x) >> 6;
    const int lane = threadIdx.x & 63;
    const int r = gw >> 2;
    const int h = gw & 3;
    const size_t base = (size_t)r * HIDD + h * 256;
    float4 xv = *(const float4*)&in[base + lane * 4];
    float ss = xv.x * xv.x + xv.y * xv.y + xv.z * xv.z + xv.w * xv.w;
    ss = waveReduceSum(ss);
    const float sc = rsqrtf(ss * (1.0f / 256.0f) + 1e-5f);
    float4 wv = *(const float4*)&w[lane * 4];
    float4 o = make_float4(xv.x * sc * wv.x, xv.y * sc * wv.y,
                           xv.z * sc * wv.z, xv.w * sc * wv.w);
    *(float4*)&out[base + lane * 4] = o;
}

extern "C" void kernel_launch(void* const* d_in, const int* in_sizes, int n_in,
                              void* d_out, int out_size, void* d_ws, size_t ws_size,
                              hipStream_t stream) {
    const float* X      = (const float*)d_in[0];
    const float* Wq     = (const float*)d_in[1];
    const float* Wk     = (const float*)d_in[2];
    const float* Wv     = (const float*)d_in[3];
    const float* Wb     = (const float*)d_in[4];
    const float* conv_q = (const float*)d_in[5];
    const float* conv_k = (const float*)d_in[6];
    const float* conv_v = (const float*)d_in[7];
    const float* norm_w = (const float*)d_in[8];
    const float* Wo     = (const float*)d_in[9];
    float* out = (float*)d_out;

    float* ws = (float*)d_ws;
    const size_t SL = (size_t)ROWS * HIDD;     // 4M floats per slot
    float* s0 = ws;                // q_pre -> kc -> o_norm
    float* s1 = ws + SL;           // k_pre -> vc
    float* s2 = ws + 2 * SL;       // v_pre -> o_raw
    float* s3 = ws + 3 * SL;       // qc
    float* betab = ws + 4 * SL;    // [4096,4]

    dim3 ggrid(HIDD / 64, ROWS / 64);   // (16, 64)

    // projections
    gemm_f32<<<ggrid, 256, 0, stream>>>(X, Wq, s0, ROWS, HIDD, HIDD);
    gemm_f32<<<ggrid, 256, 0, stream>>>(X, Wk, s1, ROWS, HIDD, HIDD);
    gemm_f32<<<ggrid, 256, 0, stream>>>(X, Wv, s2, ROWS, HIDD, HIDD);
    beta_kernel<<<ROWS / 4, 256, 0, stream>>>(X, Wb, betab);

    // conv + silu (+ l2norm for q,k)   (sequential launches allow slot reuse)
    conv_silu_kernel<<<ROWS, 256, 0, stream>>>(s0, conv_q, s3, 1);  // qc = s3
    conv_silu_kernel<<<ROWS, 256, 0, stream>>>(s1, conv_k, s0, 1);  // kc = s0
    conv_silu_kernel<<<ROWS, 256, 0, stream>>>(s2, conv_v, s1, 0);  // vc = s1

    // delta-rule scan: 8 (b,h) x 64 col-groups = 512 blocks
    delta_kernel<<<512, 256, 0, stream>>>(s3, s0, s1, betab, s2);   // o_raw = s2

    // rms norm
    rms_kernel<<<ROWS, 256, 0, stream>>>(s2, norm_w, s0);           // o_norm = s0

    // output projection
    gemm_f32<<<ggrid, 256, 0, stream>>>(s0, Wo, out, ROWS, HIDD, HIDD);
}

// Round 2
// 1023.935 us; speedup vs baseline: 1.7818x; 1.7818x over previous
//
#include <hip/hip_runtime.h>
#include <math.h>

#define BB   2
#define SS   2048
#define HIDD 1024
#define ROWS 4096
#define NCH  32      // chunks per sequence
#define CH   64      // chunk length

typedef unsigned short u16t;
typedef unsigned int   u32t;

__device__ __forceinline__ float bf2f(u16t u) { return __uint_as_float(((u32t)u) << 16); }
__device__ __forceinline__ u16t f2bf(float f) {
    u32t b = __float_as_uint(f);
    return (u16t)((b + 0x7FFFu + ((b >> 16) & 1u)) >> 16);
}
__device__ __forceinline__ float lo_bf(u32t u) { return __uint_as_float(u << 16); }
__device__ __forceinline__ float hi_bf(u32t u) { return __uint_as_float(u & 0xFFFF0000u); }

__device__ __forceinline__ float waveReduceSum(float v) {
#pragma unroll
    for (int m = 1; m < 64; m <<= 1) v += __shfl_xor(v, m, 64);
    return v;
}

// ---------------- GEMM f32 in, f32 or bf16 out -----------------------------
__global__ __launch_bounds__(256) void gemm_k(const float* __restrict__ A,
                                              const float* __restrict__ B,
                                              float* __restrict__ Cf,
                                              u16t* __restrict__ Cb, int obf,
                                              int M, int N, int K) {
    __shared__ float As[16][64];
    __shared__ float Bs[16][64];
    const int t = threadIdx.x;
    const int rowBase = blockIdx.y * 64;
    const int colBase = blockIdx.x * 64;
    const int ty = t >> 4;
    const int tx = t & 15;

    float acc[4][4];
#pragma unroll
    for (int i = 0; i < 4; ++i)
#pragma unroll
        for (int j = 0; j < 4; ++j) acc[i][j] = 0.f;

    const int am = t >> 2;
    const int ak = (t & 3) << 2;
    const int bk = t >> 4;
    const int bn = (t & 15) << 2;

    for (int k0 = 0; k0 < K; k0 += 16) {
        float4 a4 = *(const float4*)&A[(size_t)(rowBase + am) * K + k0 + ak];
        float4 b4 = *(const float4*)&B[(size_t)(k0 + bk) * N + colBase + bn];
        As[ak + 0][am] = a4.x;
        As[ak + 1][am] = a4.y;
        As[ak + 2][am] = a4.z;
        As[ak + 3][am] = a4.w;
        *(float4*)&Bs[bk][bn] = b4;
        __syncthreads();
#pragma unroll
        for (int kk = 0; kk < 16; ++kk) {
            float4 av = *(const float4*)&As[kk][ty << 2];
            float4 bv = *(const float4*)&Bs[kk][tx << 2];
            float aa[4] = {av.x, av.y, av.z, av.w};
            float bb[4] = {bv.x, bv.y, bv.z, bv.w};
#pragma unroll
            for (int i = 0; i < 4; ++i)
#pragma unroll
                for (int j = 0; j < 4; ++j) acc[i][j] += aa[i] * bb[j];
        }
        __syncthreads();
    }
    if (obf) {
#pragma unroll
        for (int i = 0; i < 4; ++i) {
            ushort4 ov;
            ov.x = f2bf(acc[i][0]); ov.y = f2bf(acc[i][1]);
            ov.z = f2bf(acc[i][2]); ov.w = f2bf(acc[i][3]);
            *(ushort4*)&Cb[(size_t)(rowBase + ty * 4 + i) * N + colBase + tx * 4] = ov;
        }
    } else {
#pragma unroll
        for (int i = 0; i < 4; ++i) {
            float4 o = make_float4(acc[i][0], acc[i][1], acc[i][2], acc[i][3]);
            *(float4*)&Cf[(size_t)(rowBase + ty * 4 + i) * N + colBase + tx * 4] = o;
        }
    }
}

// ---------------- beta = sigmoid(X @ Wb) -----------------------------------
__global__ __launch_bounds__(256) void beta_kernel(const float* __restrict__ X,
                                                   const float* __restrict__ Wb,
                                                   float* __restrict__ beta) {
    const int gw   = (blockIdx.x * blockDim.x + threadIdx.x) >> 6;
    const int lane = threadIdx.x & 63;
    if (gw >= ROWS) return;
    const float* x = X + (size_t)gw * HIDD;
    float a0 = 0.f, a1 = 0.f, a2 = 0.f, a3 = 0.f;
#pragma unroll
    for (int i = 0; i < 4; ++i) {
        const int k = lane * 16 + i * 4;
        float4 xv = *(const float4*)&x[k];
        float4 w0 = *(const float4*)&Wb[(size_t)(k + 0) * 4];
        float4 w1 = *(const float4*)&Wb[(size_t)(k + 1) * 4];
        float4 w2 = *(const float4*)&Wb[(size_t)(k + 2) * 4];
        float4 w3 = *(const float4*)&Wb[(size_t)(k + 3) * 4];
        a0 += xv.x * w0.x + xv.y * w1.x + xv.z * w2.x + xv.w * w3.x;
        a1 += xv.x * w0.y + xv.y * w1.y + xv.z * w2.y + xv.w * w3.y;
        a2 += xv.x * w0.z + xv.y * w1.z + xv.z * w2.z + xv.w * w3.z;
        a3 += xv.x * w0.w + xv.y * w1.w + xv.z * w2.w + xv.w * w3.w;
    }
    a0 = waveReduceSum(a0);
    a1 = waveReduceSum(a1);
    a2 = waveReduceSum(a2);
    a3 = waveReduceSum(a3);
    if (lane == 0) {
        float4 o = make_float4(1.f / (1.f + expf(-a0)), 1.f / (1.f + expf(-a1)),
                               1.f / (1.f + expf(-a2)), 1.f / (1.f + expf(-a3)));
        *(float4*)&beta[(size_t)gw * 4] = o;
    }
}

// ------- causal depthwise conv (K=4) + silu (+ optional l2norm), bf16 ------
__global__ __launch_bounds__(256) void conv_bf16(const u16t* __restrict__ in,
                                                 const float* __restrict__ w,
                                                 u16t* __restrict__ out, int doL2) {
    const int gw   = (blockIdx.x * blockDim.x + threadIdx.x) >> 6;
    const int lane = threadIdx.x & 63;
    const int r = gw >> 2;
    const int h = gw & 3;
    const int b = r >> 11;
    const int s = r & 2047;
    const int c4 = h * 256 + lane * 4;

    const float4 wr0 = *(const float4*)&w[(size_t)(c4 + 0) * 4];
    const float4 wr1 = *(const float4*)&w[(size_t)(c4 + 1) * 4];
    const float4 wr2 = *(const float4*)&w[(size_t)(c4 + 2) * 4];
    const float4 wr3 = *(const float4*)&w[(size_t)(c4 + 3) * 4];

    const size_t rowB = (size_t)(b << 11);
    float x0[4] = {0,0,0,0}, x1[4] = {0,0,0,0}, x2[4] = {0,0,0,0}, x3[4];
    ushort4 u;
    if (s >= 3) {
        u = *(const ushort4*)&in[(rowB + s - 3) * HIDD + c4];
        x0[0] = bf2f(u.x); x0[1] = bf2f(u.y); x0[2] = bf2f(u.z); x0[3] = bf2f(u.w);
    }
    if (s >= 2) {
        u = *(const ushort4*)&in[(rowB + s - 2) * HIDD + c4];
        x1[0] = bf2f(u.x); x1[1] = bf2f(u.y); x1[2] = bf2f(u.z); x1[3] = bf2f(u.w);
    }
    if (s >= 1) {
        u = *(const ushort4*)&in[(rowB + s - 1) * HIDD + c4];
        x2[0] = bf2f(u.x); x2[1] = bf2f(u.y); x2[2] = bf2f(u.z); x2[3] = bf2f(u.w);
    }
    u = *(const ushort4*)&in[(rowB + s) * HIDD + c4];
    x3[0] = bf2f(u.x); x3[1] = bf2f(u.y); x3[2] = bf2f(u.z); x3[3] = bf2f(u.w);

    float y0 = wr0.x * x0[0] + wr0.y * x1[0] + wr0.z * x2[0] + wr0.w * x3[0];
    float y1 = wr1.x * x0[1] + wr1.y * x1[1] + wr1.z * x2[1] + wr1.w * x3[1];
    float y2 = wr2.x * x0[2] + wr2.y * x1[2] + wr2.z * x2[2] + wr2.w * x3[2];
    float y3 = wr3.x * x0[3] + wr3.y * x1[3] + wr3.z * x2[3] + wr3.w * x3[3];

    y0 = y0 / (1.f + expf(-y0));
    y1 = y1 / (1.f + expf(-y1));
    y2 = y2 / (1.f + expf(-y2));
    y3 = y3 / (1.f + expf(-y3));

    if (doL2) {
        float ss = y0 * y0 + y1 * y1 + y2 * y2 + y3 * y3;
        ss = waveReduceSum(ss);
        float sc = rsqrtf(ss + 1e-6f);
        y0 *= sc; y1 *= sc; y2 *= sc; y3 *= sc;
    }
    ushort4 o;
    o.x = f2bf(y0); o.y = f2bf(y1); o.z = f2bf(y2); o.w = f2bf(y3);
    *(ushort4*)&out[(size_t)r * HIDD + c4] = o;
}

// ---- prep: per chunk, T = (I + strict_lower(diag(b) K K^T))^-1 and --------
// ---- attn = incl_lower(Q K^T); fully parallel over 256 chunks -------------
__global__ __launch_bounds__(256) void prep_kernel(const u16t* __restrict__ qcb,
                                                   const u16t* __restrict__ kcb,
                                                   const float* __restrict__ beta,
                                                   float* __restrict__ Tg,
                                                   float* __restrict__ Atg) {
    __shared__ float KT[256][68];   // [dk r][time i]
    __shared__ float QT[256][68];
    __shared__ float Af[64][68];
    const int t = threadIdx.x;
    const int bhc = blockIdx.x;
    const int bh = bhc >> 5, c = bhc & 31;
    const int b = bh >> 2, h = bh & 3;
    const int tb = b * SS + c * CH;

    {
        const int i = t & 63, rb = t >> 6;
        const u16t* kg = kcb + (size_t)(tb + i) * HIDD + h * 256 + rb * 64;
        const u16t* qg = qcb + (size_t)(tb + i) * HIDD + h * 256 + rb * 64;
#pragma unroll
        for (int m = 0; m < 8; ++m) {
            uint4 kv = ((const uint4*)kg)[m];
            uint4 qv = ((const uint4*)qg)[m];
            u32t kw[4] = {kv.x, kv.y, kv.z, kv.w};
            u32t qw[4] = {qv.x, qv.y, qv.z, qv.w};
#pragma unroll
            for (int n = 0; n < 4; ++n) {
                int rr = rb * 64 + m * 8 + n * 2;
                KT[rr][i]     = lo_bf(kw[n]);
                KT[rr + 1][i] = hi_bf(kw[n]);
                QT[rr][i]     = lo_bf(qw[n]);
                QT[rr + 1][i] = hi_bf(qw[n]);
            }
        }
    }
    __syncthreads();

    const int it = t & 63, jb = t >> 6;
    float kk[16], qk[16];
#pragma unroll
    for (int m = 0; m < 16; ++m) { kk[m] = 0.f; qk[m] = 0.f; }
#pragma unroll 2
    for (int r = 0; r < 256; ++r) {
        float ki = KT[r][it];
        float qi = QT[r][it];
        float4 ka = *(const float4*)&KT[r][jb * 16 + 0];
        float4 kb = *(const float4*)&KT[r][jb * 16 + 4];
        float4 kc = *(const float4*)&KT[r][jb * 16 + 8];
        float4 kd = *(const float4*)&KT[r][jb * 16 + 12];
        float kj[16] = {ka.x, ka.y, ka.z, ka.w, kb.x, kb.y, kb.z, kb.w,
                        kc.x, kc.y, kc.z, kc.w, kd.x, kd.y, kd.z, kd.w};
#pragma unroll
        for (int m = 0; m < 16; ++m) { kk[m] += ki * kj[m]; qk[m] += qi * kj[m]; }
    }

    const float bta = beta[(size_t)(tb + it) * 4 + h];
    float avals[16];
#pragma unroll
    for (int m = 0; m < 16; ++m) {
        int j = jb * 16 + m;
        Af[it][j] = (j < it) ? bta * kk[m] : 0.f;
        avals[m] = (j <= it) ? qk[m] : 0.f;
    }
    float* ag = Atg + (size_t)bhc * 4096 + (size_t)it * 64 + jb * 16;
    ((float4*)ag)[0] = make_float4(avals[0], avals[1], avals[2], avals[3]);
    ((float4*)ag)[1] = make_float4(avals[4], avals[5], avals[6], avals[7]);
    ((float4*)ag)[2] = make_float4(avals[8], avals[9], avals[10], avals[11]);
    ((float4*)ag)[3] = make_float4(avals[12], avals[13], avals[14], avals[15]);
    __syncthreads();

    if (t < 64) {
        const int ccol = t;
        float tc[64];
#pragma unroll
        for (int j = 0; j < 64; ++j) tc[j] = (j == ccol) ? 1.f : 0.f;
#pragma unroll
        for (int i = 1; i < 64; ++i) {
            float a = 0.f;
#pragma unroll
            for (int j = 0; j < i; ++j) a += Af[i][j] * tc[j];
            tc[i] -= a;
        }
        float* tg = Tg + (size_t)bhc * 4096;
#pragma unroll
        for (int i = 0; i < 64; ++i) tg[i * 64 + ccol] = tc[i];
    }
}

// ---- scan: sequential over 32 chunks, parallel over (b,h) x 32 col-blocks --
__global__ __launch_bounds__(256) void scan_kernel(const u16t* __restrict__ qcb,
                                                   const u16t* __restrict__ kcb,
                                                   const u16t* __restrict__ vcb,
                                                   const float* __restrict__ beta,
                                                   const float* __restrict__ Tg,
                                                   const float* __restrict__ Atg,
                                                   float* __restrict__ o) {
    __shared__ u32t Kb[128][66];    // pair-packed bf16: Kb[r/2][i] = K[r+1]<<16 | K[r]
    __shared__ u32t Qb[128][66];
    __shared__ float Tl[64][65];
    __shared__ float Al[64][65];
    __shared__ float Sl[256][10];   // S[r][v], v in 0..7
    __shared__ float Rl[64][8];
    __shared__ float Ul[64][8];

    const int t = threadIdx.x;
    const int bh = blockIdx.x >> 5, cb = blockIdx.x & 31;
    const int b = bh >> 2, h = bh & 3;
    const int col0 = cb * 8;
    const int it = t & 63, vp = t >> 6;

    {
        float2 z = make_float2(0.f, 0.f);
        *(float2*)&Sl[t][0] = z; *(float2*)&Sl[t][2] = z;
        *(float2*)&Sl[t][4] = z; *(float2*)&Sl[t][6] = z;
    }

    for (int c = 0; c < NCH; ++c) {
        const int tb = b * SS + c * CH;
        __syncthreads();   // prev (e)/(b) reads of Kb/Qb/Tl/Al/Ul done; Sl updated

        // stage K,Q (pair-packed, transposed)
        {
            const u16t* kg = kcb + (size_t)(tb + it) * HIDD + h * 256 + vp * 64;
            const u16t* qg = qcb + (size_t)(tb + it) * HIDD + h * 256 + vp * 64;
#pragma unroll
            for (int m = 0; m < 8; ++m) {
                uint4 kv = ((const uint4*)kg)[m];
                Kb[vp * 32 + m * 4 + 0][it] = kv.x;
                Kb[vp * 32 + m * 4 + 1][it] = kv.y;
                Kb[vp * 32 + m * 4 + 2][it] = kv.z;
                Kb[vp * 32 + m * 4 + 3][it] = kv.w;
            }
#pragma unroll
            for (int m = 0; m < 8; ++m) {
                uint4 qv = ((const uint4*)qg)[m];
                Qb[vp * 32 + m * 4 + 0][it] = qv.x;
                Qb[vp * 32 + m * 4 + 1][it] = qv.y;
                Qb[vp * 32 + m * 4 + 2][it] = qv.z;
                Qb[vp * 32 + m * 4 + 3][it] = qv.w;
            }
        }
        // stage T, attn
        {
            const int row = t >> 2, cl = (t & 3) * 16;
            const float* tgp = Tg  + (size_t)(bh * 32 + c) * 4096 + (size_t)row * 64 + cl;
            const float* agp = Atg + (size_t)(bh * 32 + c) * 4096 + (size_t)row * 64 + cl;
#pragma unroll
            for (int m = 0; m < 4; ++m) {
                float4 tv = ((const float4*)tgp)[m];
                float4 av = ((const float4*)agp)[m];
                Tl[row][cl + m * 4 + 0] = tv.x; Tl[row][cl + m * 4 + 1] = tv.y;
                Tl[row][cl + m * 4 + 2] = tv.z; Tl[row][cl + m * 4 + 3] = tv.w;
                Al[row][cl + m * 4 + 0] = av.x; Al[row][cl + m * 4 + 1] = av.y;
                Al[row][cl + m * 4 + 2] = av.z; Al[row][cl + m * 4 + 3] = av.w;
            }
        }
        // V slice + beta (registers)
        u32t vv = *(const u32t*)(vcb + (size_t)(tb + it) * HIDD + h * 256 + col0 + vp * 2);
        float vf0 = lo_bf(vv), vf1 = hi_bf(vv);
        float bta = beta[(size_t)(tb + it) * 4 + h];
        __syncthreads();

        // (a) K S0  -> rhs
        float a0 = 0.f, a1 = 0.f;
#pragma unroll 4
        for (int r2 = 0; r2 < 128; ++r2) {
            u32t kp = Kb[r2][it];
            float k0 = lo_bf(kp), k1 = hi_bf(kp);
            float2 s0 = *(const float2*)&Sl[2 * r2][2 * vp];
            float2 s1 = *(const float2*)&Sl[2 * r2 + 1][2 * vp];
            a0 += k0 * s0.x + k1 * s1.x;
            a1 += k0 * s0.y + k1 * s1.y;
        }
        Rl[it][2 * vp]     = bta * (vf0 - a0);
        Rl[it][2 * vp + 1] = bta * (vf1 - a1);
        __syncthreads();

        // (c) U = T rhs
        float u0 = 0.f, u1 = 0.f;
#pragma unroll 4
        for (int j = 0; j < 64; ++j) {
            float tv = Tl[it][j];
            float2 rr = *(const float2*)&Rl[j][2 * vp];
            u0 += tv * rr.x; u1 += tv * rr.y;
        }
        Ul[it][2 * vp]     = u0;
        Ul[it][2 * vp + 1] = u1;
        __syncthreads();

        // (d)+(b) O = attn U + Q S0
        float o0 = 0.f, o1 = 0.f;
#pragma unroll 4
        for (int j = 0; j < 64; ++j) {
            float av = Al[it][j];
            float2 uu = *(const float2*)&Ul[j][2 * vp];
            o0 += av * uu.x; o1 += av * uu.y;
        }
#pragma unroll 4
        for (int r2 = 0; r2 < 128; ++r2) {
            u32t qp = Qb[r2][it];
            float q0 = lo_bf(qp), q1 = hi_bf(qp);
            float2 s0 = *(const float2*)&Sl[2 * r2][2 * vp];
            float2 s1 = *(const float2*)&Sl[2 * r2 + 1][2 * vp];
            o0 += q0 * s0.x + q1 * s1.x;
            o1 += q0 * s0.y + q1 * s1.y;
        }
        *(float2*)&o[(size_t)(tb + it) * HIDD + h * 256 + col0 + 2 * vp] = make_float2(o0, o1);
        __syncthreads();   // (b) reads of Sl done before (e) writes

        // (e) S += K^T U : thread owns rows {2it,2it+1,128+2it,129+2it}
        float e00 = 0.f, e01 = 0.f, e10 = 0.f, e11 = 0.f;
        float e20 = 0.f, e21 = 0.f, e30 = 0.f, e31 = 0.f;
#pragma unroll 4
        for (int j = 0; j < 64; ++j) {
            u32t ka = Kb[it][j];
            u32t kb2 = Kb[64 + it][j];
            float2 uu = *(const float2*)&Ul[j][2 * vp];
            float ka0 = lo_bf(ka), ka1 = hi_bf(ka);
            float kb0 = lo_bf(kb2), kb1 = hi_bf(kb2);
            e00 += ka0 * uu.x; e01 += ka0 * uu.y;
            e10 += ka1 * uu.x; e11 += ka1 * uu.y;
            e20 += kb0 * uu.x; e21 += kb0 * uu.y;
            e30 += kb1 * uu.x; e31 += kb1 * uu.y;
        }
        float2 s;
        s = *(float2*)&Sl[2 * it][2 * vp];       s.x += e00; s.y += e01; *(float2*)&Sl[2 * it][2 * vp] = s;
        s = *(float2*)&Sl[2 * it + 1][2 * vp];   s.x += e10; s.y += e11; *(float2*)&Sl[2 * it + 1][2 * vp] = s;
        s = *(float2*)&Sl[128 + 2 * it][2 * vp]; s.x += e20; s.y += e21; *(float2*)&Sl[128 + 2 * it][2 * vp] = s;
        s = *(float2*)&Sl[129 + 2 * it][2 * vp]; s.x += e30; s.y += e31; *(float2*)&Sl[129 + 2 * it][2 * vp] = s;
    }
}

// ---------------- rms_norm over last dim (256) -----------------------------
__global__ __launch_bounds__(256) void rms_kernel(const float* __restrict__ in,
                                                  const float* __restrict__ w,
                                                  float* __restrict__ out) {
    const int gw   = (blockIdx.x * blockDim.x + threadIdx.x) >> 6;
    const int lane = threadIdx.x & 63;
    const int r = gw >> 2;
    const int h = gw & 3;
    const size_t base = (size_t)r * HIDD + h * 256;
    float4 xv = *(const float4*)&in[base + lane * 4];
    float ss = xv.x * xv.x + xv.y * xv.y + xv.z * xv.z + xv.w * xv.w;
    ss = waveReduceSum(ss);
    const float sc = rsqrtf(ss * (1.0f / 256.0f) + 1e-5f);
    float4 wv = *(const float4*)&w[lane * 4];
    float4 o = make_float4(xv.x * sc * wv.x, xv.y * sc * wv.y,
                           xv.z * sc * wv.z, xv.w * sc * wv.w);
    *(float4*)&out[base + lane * 4] = o;
}

extern "C" void kernel_launch(void* const* d_in, const int* in_sizes, int n_in,
                              void* d_out, int out_size, void* d_ws, size_t ws_size,
                              hipStream_t stream) {
    const float* X      = (const float*)d_in[0];
    const float* Wq     = (const float*)d_in[1];
    const float* Wk     = (const float*)d_in[2];
    const float* Wv     = (const float*)d_in[3];
    const float* Wb     = (const float*)d_in[4];
    const float* conv_q = (const float*)d_in[5];
    const float* conv_k = (const float*)d_in[6];
    const float* conv_v = (const float*)d_in[7];
    const float* norm_w = (const float*)d_in[8];
    const float* Wo     = (const float*)d_in[9];
    float* out = (float*)d_out;

    char* W = (char*)d_ws;
    const size_t MB = 1u << 20;
    u16t* qpre = (u16t*)(W + 0 * MB);
    u16t* kpre = (u16t*)(W + 8 * MB);
    u16t* vpre = (u16t*)(W + 16 * MB);
    u16t* qcb  = (u16t*)(W + 24 * MB);
    u16t* kcb  = (u16t*)(W + 32 * MB);
    u16t* vcb  = (u16t*)(W + 40 * MB);
    float* betab = (float*)(W + 48 * MB);
    float* Tg    = (float*)(W + 49 * MB);
    float* Atg   = (float*)(W + 53 * MB);
    float* o_raw = (float*)(W + 0 * MB);    // overlays qpre+kpre (free by then)
    float* o_nrm = (float*)(W + 16 * MB);   // overlays vpre+qcb (free by then)

    dim3 ggrid(HIDD / 64, ROWS / 64);

    gemm_k<<<ggrid, 256, 0, stream>>>(X, Wq, nullptr, qpre, 1, ROWS, HIDD, HIDD);
    gemm_k<<<ggrid, 256, 0, stream>>>(X, Wk, nullptr, kpre, 1, ROWS, HIDD, HIDD);
    gemm_k<<<ggrid, 256, 0, stream>>>(X, Wv, nullptr, vpre, 1, ROWS, HIDD, HIDD);
    beta_kernel<<<ROWS / 4, 256, 0, stream>>>(X, Wb, betab);

    conv_bf16<<<ROWS, 256, 0, stream>>>(qpre, conv_q, qcb, 1);
    conv_bf16<<<ROWS, 256, 0, stream>>>(kpre, conv_k, kcb, 1);
    conv_bf16<<<ROWS, 256, 0, stream>>>(vpre, conv_v, vcb, 0);

    prep_kernel<<<256, 256, 0, stream>>>(qcb, kcb, betab, Tg, Atg);
    scan_kernel<<<256, 256, 0, stream>>>(qcb, kcb, vcb, betab, Tg, Atg, o_raw);

    rms_kernel<<<ROWS, 256, 0, stream>>>(o_raw, norm_w, o_nrm);
    gemm_k<<<ggrid, 256, 0, stream>>>(o_nrm, Wo, out, nullptr, 0, ROWS, HIDD, HIDD);
}

// Round 3
// 316.399 us; speedup vs baseline: 5.7663x; 3.2362x over previous
//
#include <hip/hip_runtime.h>
#include <math.h>

#define BB   2
#define SS   2048
#define HIDD 1024
#define ROWS 4096
#define NCH  32
#define CH   64

typedef unsigned short u16t;
typedef unsigned int   u32t;

typedef __attribute__((ext_vector_type(8))) short bf16x8;
typedef __attribute__((ext_vector_type(4))) float f32x4;

__device__ __forceinline__ float bf2f(u16t u) { return __uint_as_float(((u32t)u) << 16); }
__device__ __forceinline__ u16t f2bf(float f) {
    u32t b = __float_as_uint(f);
    return (u16t)((b + 0x7FFFu + ((b >> 16) & 1u)) >> 16);
}
__device__ __forceinline__ float lo_bf(u32t u) { return __uint_as_float(u << 16); }
__device__ __forceinline__ float hi_bf(u32t u) { return __uint_as_float(u & 0xFFFF0000u); }

__device__ __forceinline__ float waveReduceSum(float v) {
#pragma unroll
    for (int m = 1; m < 64; m <<= 1) v += __shfl_xor(v, m, 64);
    return v;
}

__device__ __forceinline__ void gload16(const void* g, void* l) {
    __builtin_amdgcn_global_load_lds(
        (const __attribute__((address_space(1))) unsigned int*)g,
        (__attribute__((address_space(3))) unsigned int*)l, 16, 0, 0);
}

#define MFMA(a, b, c) __builtin_amdgcn_mfma_f32_16x16x32_bf16(a, b, c, 0, 0, 0)

// =================== X f32 -> bf16 ======================================
__global__ __launch_bounds__(256) void f2bf_kernel(const float* __restrict__ in,
                                                   u16t* __restrict__ out) {
    const size_t idx = ((size_t)blockIdx.x * 256 + threadIdx.x) * 8;
    float4 a = *(const float4*)&in[idx];
    float4 b = *(const float4*)&in[idx + 4];
    ushort4 o1, o2;
    o1.x = f2bf(a.x); o1.y = f2bf(a.y); o1.z = f2bf(a.z); o1.w = f2bf(a.w);
    o2.x = f2bf(b.x); o2.y = f2bf(b.y); o2.z = f2bf(b.z); o2.w = f2bf(b.w);
    *(ushort4*)&out[idx] = o1;
    *(ushort4*)&out[idx + 4] = o2;
}

// =================== W[1024][1024] f32 -> WT[n][k] bf16 =================
__global__ __launch_bounds__(256) void transpose_w(const float* __restrict__ W,
                                                   u16t* __restrict__ WT) {
    __shared__ u16t tile[64][65];
    const int t = threadIdx.x;
    const int r0 = blockIdx.y * 64, c0 = blockIdx.x * 64;
    const int lr = t >> 2, lc4 = (t & 3) * 16;
#pragma unroll
    for (int m = 0; m < 4; ++m) {
        float4 v = *(const float4*)&W[(size_t)(r0 + lr) * 1024 + c0 + lc4 + m * 4];
        tile[lr][lc4 + m * 4 + 0] = f2bf(v.x);
        tile[lr][lc4 + m * 4 + 1] = f2bf(v.y);
        tile[lr][lc4 + m * 4 + 2] = f2bf(v.z);
        tile[lr][lc4 + m * 4 + 3] = f2bf(v.w);
    }
    __syncthreads();
#pragma unroll
    for (int m = 0; m < 16; ++m)
        WT[(size_t)(c0 + lr) * 1024 + r0 + lc4 + m] = tile[lc4 + m][lr];
}

// =================== MFMA GEMM: C[M,N] = A[M,K] * BT[N,K]^T ==============
// A,BT bf16; 128x128 tile, BK=64, 256 thr (4 waves 2x2), slot-XOR swizzled LDS
__global__ __launch_bounds__(256) void gemm_mfma(const u16t* __restrict__ A,
                                                 const u16t* __restrict__ BT,
                                                 float* __restrict__ Cf,
                                                 u16t* __restrict__ Cb, int obf,
                                                 int M, int N, int K) {
    __shared__ u16t As[128 * 64];
    __shared__ u16t Bs[128 * 64];
    const int t = threadIdx.x, l = t & 63, w = t >> 6;
    const int wr = w >> 1, wc = w & 1;
    const int rowBase = blockIdx.y * 128, colBase = blockIdx.x * 128;
    const int l15 = l & 15, g4 = l >> 4;

    // staging source (pre-swizzled): lane l covers row (l>>3), slot s=l&7 holds k-block j=s^(row&7)
    const int srow = l >> 3;
    const int sj = (l & 7) ^ srow;
    const u16t* aSrc = A + (size_t)(rowBase + srow) * K + sj * 8;
    const u16t* bSrc = BT + (size_t)(colBase + srow) * K + sj * 8;

    f32x4 acc[4][4];
#pragma unroll
    for (int i = 0; i < 4; ++i)
#pragma unroll
        for (int j = 0; j < 4; ++j) acc[i][j] = (f32x4){0.f, 0.f, 0.f, 0.f};

    for (int k0 = 0; k0 < K; k0 += 64) {
#pragma unroll
        for (int i = 0; i < 4; ++i) {
            const int rb = (i * 4 + w) * 8;
            gload16(aSrc + (size_t)rb * K + k0, &As[rb * 64]);
            gload16(bSrc + (size_t)rb * K + k0, &Bs[rb * 64]);
        }
        __syncthreads();
#pragma unroll
        for (int kh = 0; kh < 2; ++kh) {
            bf16x8 aF[4], bF[4];
#pragma unroll
            for (int mi = 0; mi < 4; ++mi) {
                const int row = wr * 64 + mi * 16 + l15;
                const int phys = (kh * 4 + g4) ^ (row & 7);
                aF[mi] = *(const bf16x8*)&As[row * 64 + phys * 8];
            }
#pragma unroll
            for (int ni = 0; ni < 4; ++ni) {
                const int row = wc * 64 + ni * 16 + l15;
                const int phys = (kh * 4 + g4) ^ (row & 7);
                bF[ni] = *(const bf16x8*)&Bs[row * 64 + phys * 8];
            }
#pragma unroll
            for (int mi = 0; mi < 4; ++mi)
#pragma unroll
                for (int ni = 0; ni < 4; ++ni)
                    acc[mi][ni] = MFMA(aF[mi], bF[ni], acc[mi][ni]);
        }
        __syncthreads();
    }
    // epilogue: D row = 4*(l>>4)+reg, col = l&15
#pragma unroll
    for (int mi = 0; mi < 4; ++mi)
#pragma unroll
        for (int ni = 0; ni < 4; ++ni)
#pragma unroll
            for (int rg = 0; rg < 4; ++rg) {
                const int row = rowBase + wr * 64 + mi * 16 + g4 * 4 + rg;
                const int col = colBase + wc * 64 + ni * 16 + l15;
                const float v = acc[mi][ni][rg];
                if (obf) Cb[(size_t)row * N + col] = f2bf(v);
                else     Cf[(size_t)row * N + col] = v;
            }
}

// =================== beta = sigmoid(X @ Wb) ==============================
__global__ __launch_bounds__(256) void beta_kernel(const float* __restrict__ X,
                                                   const float* __restrict__ Wb,
                                                   float* __restrict__ beta) {
    const int gw   = (blockIdx.x * blockDim.x + threadIdx.x) >> 6;
    const int lane = threadIdx.x & 63;
    if (gw >= ROWS) return;
    const float* x = X + (size_t)gw * HIDD;
    float a0 = 0.f, a1 = 0.f, a2 = 0.f, a3 = 0.f;
#pragma unroll
    for (int i = 0; i < 4; ++i) {
        const int k = lane * 16 + i * 4;
        float4 xv = *(const float4*)&x[k];
        float4 w0 = *(const float4*)&Wb[(size_t)(k + 0) * 4];
        float4 w1 = *(const float4*)&Wb[(size_t)(k + 1) * 4];
        float4 w2 = *(const float4*)&Wb[(size_t)(k + 2) * 4];
        float4 w3 = *(const float4*)&Wb[(size_t)(k + 3) * 4];
        a0 += xv.x * w0.x + xv.y * w1.x + xv.z * w2.x + xv.w * w3.x;
        a1 += xv.x * w0.y + xv.y * w1.y + xv.z * w2.y + xv.w * w3.y;
        a2 += xv.x * w0.z + xv.y * w1.z + xv.z * w2.z + xv.w * w3.z;
        a3 += xv.x * w0.w + xv.y * w1.w + xv.z * w2.w + xv.w * w3.w;
    }
    a0 = waveReduceSum(a0); a1 = waveReduceSum(a1);
    a2 = waveReduceSum(a2); a3 = waveReduceSum(a3);
    if (lane == 0) {
        float4 o = make_float4(1.f / (1.f + expf(-a0)), 1.f / (1.f + expf(-a1)),
                               1.f / (1.f + expf(-a2)), 1.f / (1.f + expf(-a3)));
        *(float4*)&beta[(size_t)gw * 4] = o;
    }
}

// ====== causal depthwise conv(K=4)+silu(+l2norm), bf16 row-major out =====
__global__ __launch_bounds__(256) void conv_bf16(const u16t* __restrict__ in,
                                                 const float* __restrict__ w,
                                                 u16t* __restrict__ out, int doL2) {
    const int gw   = (blockIdx.x * blockDim.x + threadIdx.x) >> 6;
    const int lane = threadIdx.x & 63;
    const int r = gw >> 2;
    const int h = gw & 3;
    const int b = r >> 11;
    const int s = r & 2047;
    const int c4 = h * 256 + lane * 4;

    const float4 wr0 = *(const float4*)&w[(size_t)(c4 + 0) * 4];
    const float4 wr1 = *(const float4*)&w[(size_t)(c4 + 1) * 4];
    const float4 wr2 = *(const float4*)&w[(size_t)(c4 + 2) * 4];
    const float4 wr3 = *(const float4*)&w[(size_t)(c4 + 3) * 4];

    const size_t rowB = (size_t)(b << 11);
    float x0[4] = {0, 0, 0, 0}, x1[4] = {0, 0, 0, 0}, x2[4] = {0, 0, 0, 0}, x3[4];
    ushort4 u;
    if (s >= 3) { u = *(const ushort4*)&in[(rowB + s - 3) * HIDD + c4];
        x0[0] = bf2f(u.x); x0[1] = bf2f(u.y); x0[2] = bf2f(u.z); x0[3] = bf2f(u.w); }
    if (s >= 2) { u = *(const ushort4*)&in[(rowB + s - 2) * HIDD + c4];
        x1[0] = bf2f(u.x); x1[1] = bf2f(u.y); x1[2] = bf2f(u.z); x1[3] = bf2f(u.w); }
    if (s >= 1) { u = *(const ushort4*)&in[(rowB + s - 1) * HIDD + c4];
        x2[0] = bf2f(u.x); x2[1] = bf2f(u.y); x2[2] = bf2f(u.z); x2[3] = bf2f(u.w); }
    u = *(const ushort4*)&in[(rowB + s) * HIDD + c4];
    x3[0] = bf2f(u.x); x3[1] = bf2f(u.y); x3[2] = bf2f(u.z); x3[3] = bf2f(u.w);

    float y0 = wr0.x * x0[0] + wr0.y * x1[0] + wr0.z * x2[0] + wr0.w * x3[0];
    float y1 = wr1.x * x0[1] + wr1.y * x1[1] + wr1.z * x2[1] + wr1.w * x3[1];
    float y2 = wr2.x * x0[2] + wr2.y * x1[2] + wr2.z * x2[2] + wr2.w * x3[2];
    float y3 = wr3.x * x0[3] + wr3.y * x1[3] + wr3.z * x2[3] + wr3.w * x3[3];

    y0 = y0 / (1.f + expf(-y0)); y1 = y1 / (1.f + expf(-y1));
    y2 = y2 / (1.f + expf(-y2)); y3 = y3 / (1.f + expf(-y3));

    if (doL2) {
        float ss = y0 * y0 + y1 * y1 + y2 * y2 + y3 * y3;
        ss = waveReduceSum(ss);
        float sc = rsqrtf(ss + 1e-6f);
        y0 *= sc; y1 *= sc; y2 *= sc; y3 *= sc;
    }
    ushort4 o;
    o.x = f2bf(y0); o.y = f2bf(y1); o.z = f2bf(y2); o.w = f2bf(y3);
    *(ushort4*)&out[(size_t)r * HIDD + c4] = o;
}

// ====== conv for K: row-major out + transposed ktr[bh*256+r][t] ==========
__global__ __launch_bounds__(256) void conv_k_chunk(const u16t* __restrict__ pre,
                                                    const float* __restrict__ w,
                                                    u16t* __restrict__ rowout,
                                                    u16t* __restrict__ trout) {
    const int t = threadIdx.x;
    const int bh = blockIdx.x >> 5, c = blockIdx.x & 31;
    const int b = bh >> 2, h = bh & 3;
    const int i = t >> 2, g = t & 3;
    const int s = c * 64 + i;
    const size_t row = (size_t)b * 2048 + s;
    const int ch0 = h * 256 + g * 64;
    const int cloc = g * 64;
    float y[64];
#pragma unroll
    for (int m = 0; m < 8; ++m) {
        const int cm = ch0 + m * 8;
        uint4 x3 = *(const uint4*)&pre[row * 1024 + cm];
        uint4 x2 = (s >= 1) ? *(const uint4*)&pre[(row - 1) * 1024 + cm] : make_uint4(0, 0, 0, 0);
        uint4 x1 = (s >= 2) ? *(const uint4*)&pre[(row - 2) * 1024 + cm] : make_uint4(0, 0, 0, 0);
        uint4 x0 = (s >= 3) ? *(const uint4*)&pre[(row - 3) * 1024 + cm] : make_uint4(0, 0, 0, 0);
        u32t c0[4] = {x0.x, x0.y, x0.z, x0.w};
        u32t c1[4] = {x1.x, x1.y, x1.z, x1.w};
        u32t c2[4] = {x2.x, x2.y, x2.z, x2.w};
        u32t c3[4] = {x3.x, x3.y, x3.z, x3.w};
#pragma unroll
        for (int p = 0; p < 4; ++p) {
            const int ch = m * 8 + p * 2;
            float4 wA = *(const float4*)&w[(size_t)(ch0 + ch) * 4];
            float4 wB = *(const float4*)&w[(size_t)(ch0 + ch + 1) * 4];
            float ya = wA.x * lo_bf(c0[p]) + wA.y * lo_bf(c1[p]) + wA.z * lo_bf(c2[p]) + wA.w * lo_bf(c3[p]);
            float yb = wB.x * hi_bf(c0[p]) + wB.y * hi_bf(c1[p]) + wB.z * hi_bf(c2[p]) + wB.w * hi_bf(c3[p]);
            ya = ya / (1.f + expf(-ya));
            yb = yb / (1.f + expf(-yb));
            y[ch] = ya; y[ch + 1] = yb;
        }
    }
    float ss = 0.f;
#pragma unroll
    for (int e = 0; e < 64; ++e) ss += y[e] * y[e];
    ss += __shfl_xor(ss, 1);
    ss += __shfl_xor(ss, 2);
    const float sc = rsqrtf(ss + 1e-6f);
#pragma unroll
    for (int m = 0; m < 8; ++m) {
        uint4 o;
        u32t* op = (u32t*)&o;
#pragma unroll
        for (int p = 0; p < 4; ++p) {
            u16t a = f2bf(y[m * 8 + p * 2] * sc);
            u16t bb2 = f2bf(y[m * 8 + p * 2 + 1] * sc);
            op[p] = (u32t)a | ((u32t)bb2 << 16);
        }
        *(uint4*)&rowout[row * 1024 + ch0 + m * 8] = o;
    }
#pragma unroll
    for (int e = 0; e < 64; ++e)
        trout[((size_t)bh * 256 + cloc + e) * 2048 + s] = f2bf(y[e] * sc);
}

// ====== prep: per chunk T=(I+strict_lower(diag(b)KK^T))^-1 (bf16 hi/lo) ===
// ====== and A = incl_lower(QK^T) bf16; row-major [64][64] per chunk =======
__global__ __launch_bounds__(256) void prep_kernel(const u16t* __restrict__ qcb,
                                                   const u16t* __restrict__ kcb,
                                                   const float* __restrict__ beta,
                                                   u16t* __restrict__ Tghi,
                                                   u16t* __restrict__ Tglo,
                                                   u16t* __restrict__ Agb) {
    __shared__ float KT[256][68];
    __shared__ float QT[256][68];
    __shared__ float Af[64][68];
    const int t = threadIdx.x;
    const int bhc = blockIdx.x;
    const int bh = bhc >> 5, c = bhc & 31;
    const int b = bh >> 2, h = bh & 3;
    const int tb = b * SS + c * CH;

    {
        const int i = t & 63, rb = t >> 6;
        const u16t* kg = kcb + (size_t)(tb + i) * HIDD + h * 256 + rb * 64;
        const u16t* qg = qcb + (size_t)(tb + i) * HIDD + h * 256 + rb * 64;
#pragma unroll
        for (int m = 0; m < 8; ++m) {
            uint4 kv = ((const uint4*)kg)[m];
            uint4 qv = ((const uint4*)qg)[m];
            u32t kw[4] = {kv.x, kv.y, kv.z, kv.w};
            u32t qw[4] = {qv.x, qv.y, qv.z, qv.w};
#pragma unroll
            for (int n = 0; n < 4; ++n) {
                int rr = rb * 64 + m * 8 + n * 2;
                KT[rr][i]     = lo_bf(kw[n]);
                KT[rr + 1][i] = hi_bf(kw[n]);
                QT[rr][i]     = lo_bf(qw[n]);
                QT[rr + 1][i] = hi_bf(qw[n]);
            }
        }
    }
    __syncthreads();

    const int it = t & 63, jb = t >> 6;
    float kk[16], qk[16];
#pragma unroll
    for (int m = 0; m < 16; ++m) { kk[m] = 0.f; qk[m] = 0.f; }
#pragma unroll 2
    for (int r = 0; r < 256; ++r) {
        float ki = KT[r][it];
        float qi = QT[r][it];
        float4 ka = *(const float4*)&KT[r][jb * 16 + 0];
        float4 kb = *(const float4*)&KT[r][jb * 16 + 4];
        float4 kc = *(const float4*)&KT[r][jb * 16 + 8];
        float4 kd = *(const float4*)&KT[r][jb * 16 + 12];
        float kj[16] = {ka.x, ka.y, ka.z, ka.w, kb.x, kb.y, kb.z, kb.w,
                        kc.x, kc.y, kc.z, kc.w, kd.x, kd.y, kd.z, kd.w};
#pragma unroll
        for (int m = 0; m < 16; ++m) { kk[m] += ki * kj[m]; qk[m] += qi * kj[m]; }
    }

    const float bta = beta[(size_t)(tb + it) * 4 + h];
    u16t* ag = Agb + (size_t)bhc * 4096 + (size_t)it * 64 + jb * 16;
#pragma unroll
    for (int m = 0; m < 16; ++m) {
        int j = jb * 16 + m;
        Af[it][j] = (j < it) ? bta * kk[m] : 0.f;
    }
#pragma unroll
    for (int m4 = 0; m4 < 4; ++m4) {
        ushort4 o;
        o.x = f2bf((jb * 16 + m4 * 4 + 0 <= it) ? qk[m4 * 4 + 0] : 0.f);
        o.y = f2bf((jb * 16 + m4 * 4 + 1 <= it) ? qk[m4 * 4 + 1] : 0.f);
        o.z = f2bf((jb * 16 + m4 * 4 + 2 <= it) ? qk[m4 * 4 + 2] : 0.f);
        o.w = f2bf((jb * 16 + m4 * 4 + 3 <= it) ? qk[m4 * 4 + 3] : 0.f);
        *(ushort4*)&ag[m4 * 4] = o;
    }
    __syncthreads();

    if (t < 64) {
        const int ccol = t;
        float tc[64];
#pragma unroll
        for (int j = 0; j < 64; ++j) tc[j] = (j == ccol) ? 1.f : 0.f;
#pragma unroll
        for (int i = 1; i < 64; ++i) {
            float a = 0.f;
#pragma unroll
            for (int j = 0; j < i; ++j) a += Af[i][j] * tc[j];
            tc[i] -= a;
        }
        u16t* th = Tghi + (size_t)bhc * 4096;
        u16t* tl = Tglo + (size_t)bhc * 4096;
#pragma unroll
        for (int i = 0; i < 64; ++i) {
            u16t hi = f2bf(tc[i]);
            th[i * 64 + ccol] = hi;
            tl[i * 64 + ccol] = f2bf(tc[i] - bf2f(hi));
        }
    }
}

// ====== MFMA scan: 128 blocks = 8 bh x 16 v-tiles(16); S in acc regs ======
__global__ __launch_bounds__(256) void scan_mfma(const u16t* __restrict__ qcb,
                                                 const u16t* __restrict__ kcb,
                                                 const u16t* __restrict__ ktr,
                                                 const u16t* __restrict__ vcb,
                                                 const float* __restrict__ beta,
                                                 const u16t* __restrict__ TghiG,
                                                 const u16t* __restrict__ TgloG,
                                                 const u16t* __restrict__ AgbG,
                                                 u16t* __restrict__ o_raw) {
    __shared__ u16t Kr[64 * 256];   // [t][r] swz
    __shared__ u16t Qr[64 * 256];
    __shared__ u16t Kc[256 * 64];   // [r][t] swz
    __shared__ u16t Shi[16 * 256];  // [v][r] swz
    __shared__ u16t Slo[16 * 256];
    __shared__ u16t Thi[64 * 64];
    __shared__ u16t Tlo[64 * 64];
    __shared__ u16t Atb[64 * 64];
    __shared__ u16t Rhi[16 * 64];   // [v][t] swz
    __shared__ u16t Rlo[16 * 64];
    __shared__ u16t Uhi[16 * 64];
    __shared__ u16t Ulo[16 * 64];

    const int t = threadIdx.x, l = t & 63, w = t >> 6;
    const int bh = blockIdx.x >> 4, vt = blockIdx.x & 15;
    const int b = bh >> 2, h = bh & 3;
    const int vcol0 = vt * 16;
    const int vlow = l & 15, g4 = l >> 4;
    const int td0 = 16 * w + 4 * g4;           // D-row base (t within chunk)

    // zero S mirrors + S regs
    for (int i = t; i < 16 * 256; i += 256) { Shi[i] = 0; Slo[i] = 0; }
    f32x4 sf[4];
#pragma unroll
    for (int q = 0; q < 4; ++q) sf[q] = (f32x4){0.f, 0.f, 0.f, 0.f};
    __syncthreads();

    for (int c = 0; c < NCH; ++c) {
        const int trow0 = b * 2048 + c * 64;
        const int bhc = bh * 32 + c;

        // ---- stage (global_load_lds, pre-swizzled sources) ----
        {
            const int lr2 = l >> 5, s5 = l & 31;
            const u16t* kB = kcb + (size_t)trow0 * 1024 + h * 256;
            const u16t* qB = qcb + (size_t)trow0 * 1024 + h * 256;
#pragma unroll
            for (int i = 0; i < 8; ++i) {
                const int tb2 = (i * 4 + w) * 2;
                const int tr = tb2 + lr2;
                const int j = s5 ^ (tr & 7);
                gload16(kB + (size_t)tr * 1024 + j * 8, &Kr[tb2 * 256]);
                gload16(qB + (size_t)tr * 1024 + j * 8, &Qr[tb2 * 256]);
            }
            const int lr8 = l >> 3, s3 = l & 7;
#pragma unroll
            for (int i = 0; i < 8; ++i) {
                const int rb = (i * 4 + w) * 8;
                const int r = rb + lr8;
                const int j = s3 ^ lr8;
                gload16(ktr + ((size_t)bh * 256 + r) * 2048 + (c * 64 + j * 8), &Kc[rb * 64]);
            }
#pragma unroll
            for (int i = 0; i < 2; ++i) {
                const int rb = (i * 4 + w) * 8;
                const int r = rb + lr8;
                const int j = s3 ^ lr8;
                gload16(TghiG + (size_t)bhc * 4096 + r * 64 + j * 8, &Thi[rb * 64]);
                gload16(TgloG + (size_t)bhc * 4096 + r * 64 + j * 8, &Tlo[rb * 64]);
                gload16(AgbG + (size_t)bhc * 4096 + r * 64 + j * 8, &Atb[rb * 64]);
            }
        }
        // V, beta into regs
        float vf[4], bta[4];
#pragma unroll
        for (int rg = 0; rg < 4; ++rg) {
            vf[rg]  = bf2f(vcb[(size_t)(trow0 + td0 + rg) * 1024 + h * 256 + vcol0 + vlow]);
            bta[rg] = beta[(size_t)(trow0 + td0 + rg) * 4 + h];
        }
        __syncthreads();

        // ---- m1&2: W = K*(Shi+Slo); O1 = Q*(Shi+Slo) ----
        f32x4 Wacc = (f32x4){0.f, 0.f, 0.f, 0.f};
        f32x4 O1   = (f32x4){0.f, 0.f, 0.f, 0.f};
        const int arow = 16 * w + vlow;      // a-frag row (t)
#pragma unroll
        for (int ks = 0; ks < 8; ++ks) {
            const int physA = (4 * ks + g4) ^ (arow & 7);
            const int physB = (4 * ks + g4) ^ (vlow & 7);
            bf16x8 aK = *(const bf16x8*)&Kr[arow * 256 + physA * 8];
            bf16x8 aQ = *(const bf16x8*)&Qr[arow * 256 + physA * 8];
            bf16x8 bH = *(const bf16x8*)&Shi[vlow * 256 + physB * 8];
            bf16x8 bL = *(const bf16x8*)&Slo[vlow * 256 + physB * 8];
            Wacc = MFMA(aK, bH, Wacc); Wacc = MFMA(aK, bL, Wacc);
            O1   = MFMA(aQ, bH, O1);   O1   = MFMA(aQ, bL, O1);
        }
        // R = beta*(V - W) -> bf16 hi/lo
        {
            u16t rh[4], rl[4];
#pragma unroll
            for (int rg = 0; rg < 4; ++rg) {
                float rv = bta[rg] * (vf[rg] - Wacc[rg]);
                u16t hi = f2bf(rv);
                rh[rg] = hi;
                rl[rg] = f2bf(rv - bf2f(hi));
            }
            const int tslot = 2 * w + (g4 >> 1);
            const int base = vlow * 64 + ((tslot ^ (vlow & 7)) << 3) + ((g4 & 1) << 2);
            uint2 ph, pl;
            ph.x = (u32t)rh[0] | ((u32t)rh[1] << 16); ph.y = (u32t)rh[2] | ((u32t)rh[3] << 16);
            pl.x = (u32t)rl[0] | ((u32t)rl[1] << 16); pl.y = (u32t)rl[2] | ((u32t)rl[3] << 16);
            *(uint2*)&Rhi[base] = ph;
            *(uint2*)&Rlo[base] = pl;
        }
        __syncthreads();

        // ---- m4: U = (Thi+Tlo)*(Rhi+Rlo) ----
        f32x4 Uacc = (f32x4){0.f, 0.f, 0.f, 0.f};
#pragma unroll
        for (int ks = 0; ks < 2; ++ks) {
            const int physA = (4 * ks + g4) ^ (arow & 7);
            const int physB = (4 * ks + g4) ^ (vlow & 7);
            bf16x8 aH = *(const bf16x8*)&Thi[arow * 64 + physA * 8];
            bf16x8 aL = *(const bf16x8*)&Tlo[arow * 64 + physA * 8];
            bf16x8 bH = *(const bf16x8*)&Rhi[vlow * 64 + physB * 8];
            bf16x8 bL = *(const bf16x8*)&Rlo[vlow * 64 + physB * 8];
            Uacc = MFMA(aH, bH, Uacc);
            Uacc = MFMA(aH, bL, Uacc);
            Uacc = MFMA(aL, bH, Uacc);
        }
        {
            u16t uh[4], ul[4];
#pragma unroll
            for (int rg = 0; rg < 4; ++rg) {
                u16t hi = f2bf(Uacc[rg]);
                uh[rg] = hi;
                ul[rg] = f2bf(Uacc[rg] - bf2f(hi));
            }
            const int tslot = 2 * w + (g4 >> 1);
            const int base = vlow * 64 + ((tslot ^ (vlow & 7)) << 3) + ((g4 & 1) << 2);
            uint2 ph, pl;
            ph.x = (u32t)uh[0] | ((u32t)uh[1] << 16); ph.y = (u32t)uh[2] | ((u32t)uh[3] << 16);
            pl.x = (u32t)ul[0] | ((u32t)ul[1] << 16); pl.y = (u32t)ul[2] | ((u32t)ul[3] << 16);
            *(uint2*)&Uhi[base] = ph;
            *(uint2*)&Ulo[base] = pl;
        }
        __syncthreads();

        // ---- m5: O = O1 + A*(Uhi+Ulo); m6: S += K^T*(Uhi+Ulo) ----
        bf16x8 uhf[2], ulf[2];
#pragma unroll
        for (int ks = 0; ks < 2; ++ks) {
            const int physB = (4 * ks + g4) ^ (vlow & 7);
            uhf[ks] = *(const bf16x8*)&Uhi[vlow * 64 + physB * 8];
            ulf[ks] = *(const bf16x8*)&Ulo[vlow * 64 + physB * 8];
        }
        f32x4 Oacc = O1;
#pragma unroll
        for (int ks = 0; ks < 2; ++ks) {
            const int physA = (4 * ks + g4) ^ (arow & 7);
            bf16x8 aA = *(const bf16x8*)&Atb[arow * 64 + physA * 8];
            Oacc = MFMA(aA, uhf[ks], Oacc);
            Oacc = MFMA(aA, ulf[ks], Oacc);
        }
#pragma unroll
        for (int rg = 0; rg < 4; ++rg)
            o_raw[(size_t)(trow0 + td0 + rg) * 1024 + h * 256 + vcol0 + vlow] = f2bf(Oacc[rg]);

#pragma unroll
        for (int q = 0; q < 4; ++q) {
            const int rrow = 64 * w + 16 * q + vlow;
#pragma unroll
            for (int ks = 0; ks < 2; ++ks) {
                const int physA = (4 * ks + g4) ^ (rrow & 7);
                bf16x8 aC = *(const bf16x8*)&Kc[rrow * 64 + physA * 8];
                sf[q] = MFMA(aC, uhf[ks], sf[q]);
                sf[q] = MFMA(aC, ulf[ks], sf[q]);
            }
        }
        // refresh S mirrors
#pragma unroll
        for (int q = 0; q < 4; ++q) {
            u16t sh[4], sl[4];
#pragma unroll
            for (int rg = 0; rg < 4; ++rg) {
                u16t hi = f2bf(sf[q][rg]);
                sh[rg] = hi;
                sl[rg] = f2bf(sf[q][rg] - bf2f(hi));
            }
            const int rslot = 8 * w + 2 * q + (g4 >> 1);
            const int base = vlow * 256 + ((rslot ^ (vlow & 7)) << 3) + ((g4 & 1) << 2);
            uint2 ph, pl;
            ph.x = (u32t)sh[0] | ((u32t)sh[1] << 16); ph.y = (u32t)sh[2] | ((u32t)sh[3] << 16);
            pl.x = (u32t)sl[0] | ((u32t)sl[1] << 16); pl.y = (u32t)sl[2] | ((u32t)sl[3] << 16);
            *(uint2*)&Shi[base] = ph;
            *(uint2*)&Slo[base] = pl;
        }
        __syncthreads();
    }
}

// =================== rms_norm (bf16 in -> bf16 out) ======================
__global__ __launch_bounds__(256) void rms_kernel(const u16t* __restrict__ in,
                                                  const float* __restrict__ w,
                                                  u16t* __restrict__ out) {
    const int gw   = (blockIdx.x * blockDim.x + threadIdx.x) >> 6;
    const int lane = threadIdx.x & 63;
    const int r = gw >> 2;
    const int h = gw & 3;
    const size_t base = (size_t)r * HIDD + h * 256 + lane * 4;
    ushort4 xv = *(const ushort4*)&in[base];
    float x0 = bf2f(xv.x), x1 = bf2f(xv.y), x2 = bf2f(xv.z), x3 = bf2f(xv.w);
    float ss = x0 * x0 + x1 * x1 + x2 * x2 + x3 * x3;
    ss = waveReduceSum(ss);
    const float sc = rsqrtf(ss * (1.0f / 256.0f) + 1e-5f);
    float4 wv = *(const float4*)&w[lane * 4];
    ushort4 o;
    o.x = f2bf(x0 * sc * wv.x); o.y = f2bf(x1 * sc * wv.y);
    o.z = f2bf(x2 * sc * wv.z); o.w = f2bf(x3 * sc * wv.w);
    *(ushort4*)&out[base] = o;
}

extern "C" void kernel_launch(void* const* d_in, const int* in_sizes, int n_in,
                              void* d_out, int out_size, void* d_ws, size_t ws_size,
                              hipStream_t stream) {
    const float* X      = (const float*)d_in[0];
    const float* Wq     = (const float*)d_in[1];
    const float* Wk     = (const float*)d_in[2];
    const float* Wv     = (const float*)d_in[3];
    const float* Wb     = (const float*)d_in[4];
    const float* conv_q = (const float*)d_in[5];
    const float* conv_k = (const float*)d_in[6];
    const float* conv_v = (const float*)d_in[7];
    const float* norm_w = (const float*)d_in[8];
    const float* Wo     = (const float*)d_in[9];
    float* out = (float*)d_out;

    char* W8 = (char*)d_ws;
    const size_t MB = 1u << 20;
    u16t* Xbf   = (u16t*)(W8 + 0 * MB);    // -> o_raw after projections
    u16t* o_raw = Xbf;
    u16t* qpre  = (u16t*)(W8 + 8 * MB);    // -> o_nrm after conv_q
    u16t* o_nrm = qpre;
    u16t* kpre  = (u16t*)(W8 + 16 * MB);   // -> Tghi/Tglo/Agb after conv_k
    u16t* Tghi  = (u16t*)(W8 + 16 * MB);
    u16t* Tglo  = (u16t*)(W8 + 18 * MB);
    u16t* Agb   = (u16t*)(W8 + 20 * MB);
    u16t* vpre  = (u16t*)(W8 + 24 * MB);   // -> ktr after conv_v
    u16t* ktr   = (u16t*)(W8 + 24 * MB);
    u16t* WqT   = (u16t*)(W8 + 32 * MB);   // -> qcb after gemm_q
    u16t* qcb   = (u16t*)(W8 + 32 * MB);
    u16t* WkT   = (u16t*)(W8 + 40 * MB);   // -> kcb
    u16t* kcb   = (u16t*)(W8 + 40 * MB);
    u16t* WvT   = (u16t*)(W8 + 48 * MB);   // -> vcb
    u16t* vcb   = (u16t*)(W8 + 48 * MB);
    u16t* WoT   = (u16t*)(W8 + 56 * MB);
    float* betab = (float*)(W8 + 58 * MB);

    dim3 tgrid(16, 16);
    f2bf_kernel<<<2048, 256, 0, stream>>>(X, Xbf);
    transpose_w<<<tgrid, 256, 0, stream>>>(Wq, WqT);
    transpose_w<<<tgrid, 256, 0, stream>>>(Wk, WkT);
    transpose_w<<<tgrid, 256, 0, stream>>>(Wv, WvT);
    transpose_w<<<tgrid, 256, 0, stream>>>(Wo, WoT);

    dim3 ggrid(HIDD / 128, ROWS / 128);   // (8, 32)
    gemm_mfma<<<ggrid, 256, 0, stream>>>(Xbf, WqT, nullptr, qpre, 1, ROWS, HIDD, HIDD);
    gemm_mfma<<<ggrid, 256, 0, stream>>>(Xbf, WkT, nullptr, kpre, 1, ROWS, HIDD, HIDD);
    gemm_mfma<<<ggrid, 256, 0, stream>>>(Xbf, WvT, nullptr, vpre, 1, ROWS, HIDD, HIDD);
    beta_kernel<<<ROWS / 4, 256, 0, stream>>>(X, Wb, betab);

    conv_bf16<<<ROWS, 256, 0, stream>>>(vpre, conv_v, vcb, 0);      // frees vpre
    conv_bf16<<<ROWS, 256, 0, stream>>>(qpre, conv_q, qcb, 1);
    conv_k_chunk<<<256, 256, 0, stream>>>(kpre, conv_k, kcb, ktr);  // ktr over vpre

    prep_kernel<<<256, 256, 0, stream>>>(qcb, kcb, betab, Tghi, Tglo, Agb);
    scan_mfma<<<128, 256, 0, stream>>>(qcb, kcb, ktr, vcb, betab, Tghi, Tglo, Agb, o_raw);

    rms_kernel<<<ROWS, 256, 0, stream>>>(o_raw, norm_w, o_nrm);
    gemm_mfma<<<ggrid, 256, 0, stream>>>(o_nrm, WoT, out, nullptr, 0, ROWS, HIDD, HIDD);
}

// Round 4
// 293.936 us; speedup vs baseline: 6.2069x; 1.0764x over previous
//
#include <hip/hip_runtime.h>
#include <math.h>

#define BB   2
#define SS   2048
#define HIDD 1024
#define ROWS 4096
#define NCH  32
#define CH   64

typedef unsigned short u16t;
typedef unsigned int   u32t;

typedef __attribute__((ext_vector_type(8))) short bf16x8;
typedef __attribute__((ext_vector_type(4))) float f32x4;

__device__ __forceinline__ float bf2f(u16t u) { return __uint_as_float(((u32t)u) << 16); }
__device__ __forceinline__ u16t f2bf(float f) {
    u32t b = __float_as_uint(f);
    return (u16t)((b + 0x7FFFu + ((b >> 16) & 1u)) >> 16);
}
__device__ __forceinline__ float lo_bf(u32t u) { return __uint_as_float(u << 16); }
__device__ __forceinline__ float hi_bf(u32t u) { return __uint_as_float(u & 0xFFFF0000u); }

__device__ __forceinline__ float waveReduceSum(float v) {
#pragma unroll
    for (int m = 1; m < 64; m <<= 1) v += __shfl_xor(v, m, 64);
    return v;
}

__device__ __forceinline__ void gload16(const void* g, void* l) {
    __builtin_amdgcn_global_load_lds(
        (const __attribute__((address_space(1))) unsigned int*)g,
        (__attribute__((address_space(3))) unsigned int*)l, 16, 0, 0);
}

#define MFMA(a, b, c) __builtin_amdgcn_mfma_f32_16x16x32_bf16(a, b, c, 0, 0, 0)

// =================== X f32 -> bf16 ======================================
__global__ __launch_bounds__(256) void f2bf_kernel(const float* __restrict__ in,
                                                   u16t* __restrict__ out) {
    const size_t idx = ((size_t)blockIdx.x * 256 + threadIdx.x) * 8;
    float4 a = *(const float4*)&in[idx];
    float4 b = *(const float4*)&in[idx + 4];
    ushort4 o1, o2;
    o1.x = f2bf(a.x); o1.y = f2bf(a.y); o1.z = f2bf(a.z); o1.w = f2bf(a.w);
    o2.x = f2bf(b.x); o2.y = f2bf(b.y); o2.z = f2bf(b.z); o2.w = f2bf(b.w);
    *(ushort4*)&out[idx] = o1;
    *(ushort4*)&out[idx + 4] = o2;
}

// =================== W[1024][1024] f32 -> WT[n][k] bf16 =================
__global__ __launch_bounds__(256) void transpose_w(const float* __restrict__ W,
                                                   u16t* __restrict__ WT) {
    __shared__ u16t tile[64][65];
    const int t = threadIdx.x;
    const int r0 = blockIdx.y * 64, c0 = blockIdx.x * 64;
    const int lr = t >> 2, lc4 = (t & 3) * 16;
#pragma unroll
    for (int m = 0; m < 4; ++m) {
        float4 v = *(const float4*)&W[(size_t)(r0 + lr) * 1024 + c0 + lc4 + m * 4];
        tile[lr][lc4 + m * 4 + 0] = f2bf(v.x);
        tile[lr][lc4 + m * 4 + 1] = f2bf(v.y);
        tile[lr][lc4 + m * 4 + 2] = f2bf(v.z);
        tile[lr][lc4 + m * 4 + 3] = f2bf(v.w);
    }
    __syncthreads();
#pragma unroll
    for (int m = 0; m < 16; ++m)
        WT[(size_t)(c0 + lr) * 1024 + r0 + lc4 + m] = tile[lc4 + m][lr];
}

// ======= MFMA GEMM: C[M,N] = A[M,K] * BT[N,K]^T, plane-strided B/C =======
// A,BT bf16; 128x128 tile, BK=64, 256 thr (4 waves 2x2), slot-XOR swizzled LDS
__global__ __launch_bounds__(256) void gemm_mfma(const u16t* __restrict__ A,
                                                 const u16t* __restrict__ BT,
                                                 float* __restrict__ Cf,
                                                 u16t* __restrict__ Cb, int obf,
                                                 int M, int N, int K,
                                                 size_t bStrideP, size_t cStrideP) {
    __shared__ u16t As[128 * 64];
    __shared__ u16t Bs[128 * 64];
    const int t = threadIdx.x, l = t & 63, w = t >> 6;
    const int wr = w >> 1, wc = w & 1;
    const int rowBase = blockIdx.y * 128, colBase = blockIdx.x * 128;
    const int l15 = l & 15, g4 = l >> 4;

    const int bplane = colBase >> 10;
    const int bcol = colBase & 1023;

    const int srow = l >> 3;
    const int sj = (l & 7) ^ srow;
    const u16t* aSrc = A + (size_t)(rowBase + srow) * K + sj * 8;
    const u16t* bSrc = BT + (size_t)bplane * bStrideP + (size_t)(bcol + srow) * K + sj * 8;

    f32x4 acc[4][4];
#pragma unroll
    for (int i = 0; i < 4; ++i)
#pragma unroll
        for (int j = 0; j < 4; ++j) acc[i][j] = (f32x4){0.f, 0.f, 0.f, 0.f};

    for (int k0 = 0; k0 < K; k0 += 64) {
#pragma unroll
        for (int i = 0; i < 4; ++i) {
            const int rb = (i * 4 + w) * 8;
            gload16(aSrc + (size_t)rb * K + k0, &As[rb * 64]);
            gload16(bSrc + (size_t)rb * K + k0, &Bs[rb * 64]);
        }
        __syncthreads();
#pragma unroll
        for (int kh = 0; kh < 2; ++kh) {
            bf16x8 aF[4], bF[4];
#pragma unroll
            for (int mi = 0; mi < 4; ++mi) {
                const int row = wr * 64 + mi * 16 + l15;
                const int phys = (kh * 4 + g4) ^ (row & 7);
                aF[mi] = *(const bf16x8*)&As[row * 64 + phys * 8];
            }
#pragma unroll
            for (int ni = 0; ni < 4; ++ni) {
                const int row = wc * 64 + ni * 16 + l15;
                const int phys = (kh * 4 + g4) ^ (row & 7);
                bF[ni] = *(const bf16x8*)&Bs[row * 64 + phys * 8];
            }
#pragma unroll
            for (int mi = 0; mi < 4; ++mi)
#pragma unroll
                for (int ni = 0; ni < 4; ++ni)
                    acc[mi][ni] = MFMA(aF[mi], bF[ni], acc[mi][ni]);
        }
        __syncthreads();
    }
#pragma unroll
    for (int mi = 0; mi < 4; ++mi)
#pragma unroll
        for (int ni = 0; ni < 4; ++ni)
#pragma unroll
            for (int rg = 0; rg < 4; ++rg) {
                const int row = rowBase + wr * 64 + mi * 16 + g4 * 4 + rg;
                const int col = colBase + wc * 64 + ni * 16 + l15;
                const int plane = col >> 10, cc = col & 1023;
                const float v = acc[mi][ni][rg];
                if (obf) Cb[(size_t)plane * cStrideP + (size_t)row * 1024 + cc] = f2bf(v);
                else     Cf[(size_t)plane * cStrideP + (size_t)row * 1024 + cc] = v;
            }
}

// =================== beta = sigmoid(X @ Wb) ==============================
__global__ __launch_bounds__(256) void beta_kernel(const float* __restrict__ X,
                                                   const float* __restrict__ Wb,
                                                   float* __restrict__ beta) {
    const int gw   = (blockIdx.x * blockDim.x + threadIdx.x) >> 6;
    const int lane = threadIdx.x & 63;
    if (gw >= ROWS) return;
    const float* x = X + (size_t)gw * HIDD;
    float a0 = 0.f, a1 = 0.f, a2 = 0.f, a3 = 0.f;
#pragma unroll
    for (int i = 0; i < 4; ++i) {
        const int k = lane * 16 + i * 4;
        float4 xv = *(const float4*)&x[k];
        float4 w0 = *(const float4*)&Wb[(size_t)(k + 0) * 4];
        float4 w1 = *(const float4*)&Wb[(size_t)(k + 1) * 4];
        float4 w2 = *(const float4*)&Wb[(size_t)(k + 2) * 4];
        float4 w3 = *(const float4*)&Wb[(size_t)(k + 3) * 4];
        a0 += xv.x * w0.x + xv.y * w1.x + xv.z * w2.x + xv.w * w3.x;
        a1 += xv.x * w0.y + xv.y * w1.y + xv.z * w2.y + xv.w * w3.y;
        a2 += xv.x * w0.z + xv.y * w1.z + xv.z * w2.z + xv.w * w3.z;
        a3 += xv.x * w0.w + xv.y * w1.w + xv.z * w2.w + xv.w * w3.w;
    }
    a0 = waveReduceSum(a0); a1 = waveReduceSum(a1);
    a2 = waveReduceSum(a2); a3 = waveReduceSum(a3);
    if (lane == 0) {
        float4 o = make_float4(1.f / (1.f + expf(-a0)), 1.f / (1.f + expf(-a1)),
                               1.f / (1.f + expf(-a2)), 1.f / (1.f + expf(-a3)));
        *(float4*)&beta[(size_t)gw * 4] = o;
    }
}

// ====== causal depthwise conv(K=4)+silu(+l2norm), bf16 row-major out =====
__global__ __launch_bounds__(256) void conv_bf16(const u16t* __restrict__ in,
                                                 const float* __restrict__ w,
                                                 u16t* __restrict__ out, int doL2) {
    const int gw   = (blockIdx.x * blockDim.x + threadIdx.x) >> 6;
    const int lane = threadIdx.x & 63;
    const int r = gw >> 2;
    const int h = gw & 3;
    const int b = r >> 11;
    const int s = r & 2047;
    const int c4 = h * 256 + lane * 4;

    const float4 wr0 = *(const float4*)&w[(size_t)(c4 + 0) * 4];
    const float4 wr1 = *(const float4*)&w[(size_t)(c4 + 1) * 4];
    const float4 wr2 = *(const float4*)&w[(size_t)(c4 + 2) * 4];
    const float4 wr3 = *(const float4*)&w[(size_t)(c4 + 3) * 4];

    const size_t rowB = (size_t)(b << 11);
    float x0[4] = {0, 0, 0, 0}, x1[4] = {0, 0, 0, 0}, x2[4] = {0, 0, 0, 0}, x3[4];
    ushort4 u;
    if (s >= 3) { u = *(const ushort4*)&in[(rowB + s - 3) * HIDD + c4];
        x0[0] = bf2f(u.x); x0[1] = bf2f(u.y); x0[2] = bf2f(u.z); x0[3] = bf2f(u.w); }
    if (s >= 2) { u = *(const ushort4*)&in[(rowB + s - 2) * HIDD + c4];
        x1[0] = bf2f(u.x); x1[1] = bf2f(u.y); x1[2] = bf2f(u.z); x1[3] = bf2f(u.w); }
    if (s >= 1) { u = *(const ushort4*)&in[(rowB + s - 1) * HIDD + c4];
        x2[0] = bf2f(u.x); x2[1] = bf2f(u.y); x2[2] = bf2f(u.z); x2[3] = bf2f(u.w); }
    u = *(const ushort4*)&in[(rowB + s) * HIDD + c4];
    x3[0] = bf2f(u.x); x3[1] = bf2f(u.y); x3[2] = bf2f(u.z); x3[3] = bf2f(u.w);

    float y0 = wr0.x * x0[0] + wr0.y * x1[0] + wr0.z * x2[0] + wr0.w * x3[0];
    float y1 = wr1.x * x0[1] + wr1.y * x1[1] + wr1.z * x2[1] + wr1.w * x3[1];
    float y2 = wr2.x * x0[2] + wr2.y * x1[2] + wr2.z * x2[2] + wr2.w * x3[2];
    float y3 = wr3.x * x0[3] + wr3.y * x1[3] + wr3.z * x2[3] + wr3.w * x3[3];

    y0 = y0 / (1.f + expf(-y0)); y1 = y1 / (1.f + expf(-y1));
    y2 = y2 / (1.f + expf(-y2)); y3 = y3 / (1.f + expf(-y3));

    if (doL2) {
        float ss = y0 * y0 + y1 * y1 + y2 * y2 + y3 * y3;
        ss = waveReduceSum(ss);
        float sc = rsqrtf(ss + 1e-6f);
        y0 *= sc; y1 *= sc; y2 *= sc; y3 *= sc;
    }
    ushort4 o;
    o.x = f2bf(y0); o.y = f2bf(y1); o.z = f2bf(y2); o.w = f2bf(y3);
    *(ushort4*)&out[(size_t)r * HIDD + c4] = o;
}

// ====== conv for K: row-major out + transposed ktr[bh*256+r][t] ==========
__global__ __launch_bounds__(256) void conv_k_chunk(const u16t* __restrict__ pre,
                                                    const float* __restrict__ w,
                                                    u16t* __restrict__ rowout,
                                                    u16t* __restrict__ trout) {
    const int t = threadIdx.x;
    const int bh = blockIdx.x >> 5, c = blockIdx.x & 31;
    const int b = bh >> 2, h = bh & 3;
    const int i = t >> 2, g = t & 3;
    const int s = c * 64 + i;
    const size_t row = (size_t)b * 2048 + s;
    const int ch0 = h * 256 + g * 64;
    const int cloc = g * 64;
    float y[64];
#pragma unroll
    for (int m = 0; m < 8; ++m) {
        const int cm = ch0 + m * 8;
        uint4 x3 = *(const uint4*)&pre[row * 1024 + cm];
        uint4 x2 = (s >= 1) ? *(const uint4*)&pre[(row - 1) * 1024 + cm] : make_uint4(0, 0, 0, 0);
        uint4 x1 = (s >= 2) ? *(const uint4*)&pre[(row - 2) * 1024 + cm] : make_uint4(0, 0, 0, 0);
        uint4 x0 = (s >= 3) ? *(const uint4*)&pre[(row - 3) * 1024 + cm] : make_uint4(0, 0, 0, 0);
        u32t c0[4] = {x0.x, x0.y, x0.z, x0.w};
        u32t c1[4] = {x1.x, x1.y, x1.z, x1.w};
        u32t c2[4] = {x2.x, x2.y, x2.z, x2.w};
        u32t c3[4] = {x3.x, x3.y, x3.z, x3.w};
#pragma unroll
        for (int p = 0; p < 4; ++p) {
            const int ch = m * 8 + p * 2;
            float4 wA = *(const float4*)&w[(size_t)(ch0 + ch) * 4];
            float4 wB = *(const float4*)&w[(size_t)(ch0 + ch + 1) * 4];
            float ya = wA.x * lo_bf(c0[p]) + wA.y * lo_bf(c1[p]) + wA.z * lo_bf(c2[p]) + wA.w * lo_bf(c3[p]);
            float yb = wB.x * hi_bf(c0[p]) + wB.y * hi_bf(c1[p]) + wB.z * hi_bf(c2[p]) + wB.w * hi_bf(c3[p]);
            ya = ya / (1.f + expf(-ya));
            yb = yb / (1.f + expf(-yb));
            y[ch] = ya; y[ch + 1] = yb;
        }
    }
    float ss = 0.f;
#pragma unroll
    for (int e = 0; e < 64; ++e) ss += y[e] * y[e];
    ss += __shfl_xor(ss, 1);
    ss += __shfl_xor(ss, 2);
    const float sc = rsqrtf(ss + 1e-6f);
#pragma unroll
    for (int m = 0; m < 8; ++m) {
        uint4 o;
        u32t* op = (u32t*)&o;
#pragma unroll
        for (int p = 0; p < 4; ++p) {
            u16t a = f2bf(y[m * 8 + p * 2] * sc);
            u16t bb2 = f2bf(y[m * 8 + p * 2 + 1] * sc);
            op[p] = (u32t)a | ((u32t)bb2 << 16);
        }
        *(uint4*)&rowout[row * 1024 + ch0 + m * 8] = o;
    }
#pragma unroll
    for (int e = 0; e < 64; ++e)
        trout[((size_t)bh * 256 + cloc + e) * 2048 + s] = f2bf(y[e] * sc);
}

// ====== prep: per chunk T=(I+strict_lower(diag(b)KK^T))^-1 (bf16 hi/lo) ===
// ====== and A = incl_lower(QK^T) bf16; row-major [64][64] per chunk =======
__global__ __launch_bounds__(256) void prep_kernel(const u16t* __restrict__ qcb,
                                                   const u16t* __restrict__ kcb,
                                                   const float* __restrict__ beta,
                                                   u16t* __restrict__ Tghi,
                                                   u16t* __restrict__ Tglo,
                                                   u16t* __restrict__ Agb) {
    __shared__ float KT[256][68];
    __shared__ float QT[256][68];
    __shared__ float Af[64][68];
    const int t = threadIdx.x;
    const int bhc = blockIdx.x;
    const int bh = bhc >> 5, c = bhc & 31;
    const int b = bh >> 2, h = bh & 3;
    const int tb = b * SS + c * CH;

    {
        const int i = t & 63, rb = t >> 6;
        const u16t* kg = kcb + (size_t)(tb + i) * HIDD + h * 256 + rb * 64;
        const u16t* qg = qcb + (size_t)(tb + i) * HIDD + h * 256 + rb * 64;
#pragma unroll
        for (int m = 0; m < 8; ++m) {
            uint4 kv = ((const uint4*)kg)[m];
            uint4 qv = ((const uint4*)qg)[m];
            u32t kw[4] = {kv.x, kv.y, kv.z, kv.w};
            u32t qw[4] = {qv.x, qv.y, qv.z, qv.w};
#pragma unroll
            for (int n = 0; n < 4; ++n) {
                int rr = rb * 64 + m * 8 + n * 2;
                KT[rr][i]     = lo_bf(kw[n]);
                KT[rr + 1][i] = hi_bf(kw[n]);
                QT[rr][i]     = lo_bf(qw[n]);
                QT[rr + 1][i] = hi_bf(qw[n]);
            }
        }
    }
    __syncthreads();

    const int it = t & 63, jb = t >> 6;
    float kk[16], qk[16];
#pragma unroll
    for (int m = 0; m < 16; ++m) { kk[m] = 0.f; qk[m] = 0.f; }
#pragma unroll 2
    for (int r = 0; r < 256; ++r) {
        float ki = KT[r][it];
        float qi = QT[r][it];
        float4 ka = *(const float4*)&KT[r][jb * 16 + 0];
        float4 kb = *(const float4*)&KT[r][jb * 16 + 4];
        float4 kc = *(const float4*)&KT[r][jb * 16 + 8];
        float4 kd = *(const float4*)&KT[r][jb * 16 + 12];
        float kj[16] = {ka.x, ka.y, ka.z, ka.w, kb.x, kb.y, kb.z, kb.w,
                        kc.x, kc.y, kc.z, kc.w, kd.x, kd.y, kd.z, kd.w};
#pragma unroll
        for (int m = 0; m < 16; ++m) { kk[m] += ki * kj[m]; qk[m] += qi * kj[m]; }
    }

    const float bta = beta[(size_t)(tb + it) * 4 + h];
    u16t* ag = Agb + (size_t)bhc * 4096 + (size_t)it * 64 + jb * 16;
#pragma unroll
    for (int m = 0; m < 16; ++m) {
        int j = jb * 16 + m;
        Af[it][j] = (j < it) ? bta * kk[m] : 0.f;
    }
#pragma unroll
    for (int m4 = 0; m4 < 4; ++m4) {
        ushort4 o;
        o.x = f2bf((jb * 16 + m4 * 4 + 0 <= it) ? qk[m4 * 4 + 0] : 0.f);
        o.y = f2bf((jb * 16 + m4 * 4 + 1 <= it) ? qk[m4 * 4 + 1] : 0.f);
        o.z = f2bf((jb * 16 + m4 * 4 + 2 <= it) ? qk[m4 * 4 + 2] : 0.f);
        o.w = f2bf((jb * 16 + m4 * 4 + 3 <= it) ? qk[m4 * 4 + 3] : 0.f);
        *(ushort4*)&ag[m4 * 4] = o;
    }
    __syncthreads();

    if (t < 64) {
        const int ccol = t;
        float tc[64];
#pragma unroll
        for (int j = 0; j < 64; ++j) tc[j] = (j == ccol) ? 1.f : 0.f;
#pragma unroll
        for (int i = 1; i < 64; ++i) {
            float a = 0.f;
#pragma unroll
            for (int j = 0; j < i; ++j) a += Af[i][j] * tc[j];
            tc[i] -= a;
        }
        u16t* th = Tghi + (size_t)bhc * 4096;
        u16t* tl = Tglo + (size_t)bhc * 4096;
#pragma unroll
        for (int i = 0; i < 64; ++i) {
            u16t hi = f2bf(tc[i]);
            th[i * 64 + ccol] = hi;
            tl[i * 64 + ccol] = f2bf(tc[i] - bf2f(hi));
        }
    }
}

// ====== MFMA scan v2: all A-operands in registers, prefetched 1 chunk ahead
// ====== LDS only for S mirrors and R/U transposes; 3 barriers per chunk ===
__global__ __launch_bounds__(256, 1) void scan_mfma(const u16t* __restrict__ qcb,
                                                    const u16t* __restrict__ kcb,
                                                    const u16t* __restrict__ ktr,
                                                    const u16t* __restrict__ vcb,
                                                    const float* __restrict__ beta,
                                                    const u16t* __restrict__ TghiG,
                                                    const u16t* __restrict__ TgloG,
                                                    const u16t* __restrict__ AgbG,
                                                    u16t* __restrict__ o_raw) {
    __shared__ u16t Shi[16 * 256];  // [v][r] slot-XOR swizzled
    __shared__ u16t Slo[16 * 256];
    __shared__ u16t Rhi[16 * 64];   // [v][t] slot-XOR swizzled
    __shared__ u16t Rlo[16 * 64];
    __shared__ u16t Uhi[16 * 64];
    __shared__ u16t Ulo[16 * 64];

    const int t = threadIdx.x, l = t & 63, w = t >> 6;
    const int bh = blockIdx.x >> 4, vt = blockIdx.x & 15;
    const int b = bh >> 2, h = bh & 3;
    const int vcol0 = vt * 16;
    const int vlow = l & 15, g4 = l >> 4;

    for (int i = t; i < 16 * 256; i += 256) { Shi[i] = 0; Slo[i] = 0; }
    f32x4 sf[4];
#pragma unroll
    for (int q = 0; q < 4; ++q) sf[q] = (f32x4){0.f, 0.f, 0.f, 0.f};

    // register-resident A-fragments (wave-private operands)
    bf16x8 kf[8], qf[8], tfh[2], tfl[2], af[2], kcf[8];
    u16t vfb[4];
    float bta[4];

    auto loadKQ = [&](int c) {
        const size_t rb = (size_t)(b * 2048 + c * 64 + 16 * w + vlow) * 1024 + h * 256 + g4 * 8;
#pragma unroll
        for (int ks = 0; ks < 8; ++ks) {
            kf[ks] = *(const bf16x8*)(kcb + rb + ks * 32);
            qf[ks] = *(const bf16x8*)(qcb + rb + ks * 32);
        }
    };
    auto loadVB = [&](int c) {
        const int r0 = b * 2048 + c * 64 + 16 * w + 4 * g4;
#pragma unroll
        for (int rg = 0; rg < 4; ++rg) {
            vfb[rg] = vcb[(size_t)(r0 + rg) * 1024 + h * 256 + vcol0 + vlow];
            bta[rg] = beta[(size_t)(r0 + rg) * 4 + h];
        }
    };
    auto loadT = [&](int c) {
        const size_t tb2 = (size_t)(bh * 32 + c) * 4096 + (size_t)(16 * w + vlow) * 64 + g4 * 8;
        tfh[0] = *(const bf16x8*)(TghiG + tb2);
        tfh[1] = *(const bf16x8*)(TghiG + tb2 + 32);
        tfl[0] = *(const bf16x8*)(TgloG + tb2);
        tfl[1] = *(const bf16x8*)(TgloG + tb2 + 32);
    };
    auto loadA = [&](int c) {
        const size_t tb2 = (size_t)(bh * 32 + c) * 4096 + (size_t)(16 * w + vlow) * 64 + g4 * 8;
        af[0] = *(const bf16x8*)(AgbG + tb2);
        af[1] = *(const bf16x8*)(AgbG + tb2 + 32);
    };
    auto loadKC = [&](int c) {
        const size_t cb2 = ((size_t)bh * 256 + 64 * w + vlow) * 2048 + c * 64 + g4 * 8;
#pragma unroll
        for (int q2 = 0; q2 < 4; ++q2) {
            kcf[q2 * 2 + 0] = *(const bf16x8*)(ktr + cb2 + (size_t)(16 * q2) * 2048);
            kcf[q2 * 2 + 1] = *(const bf16x8*)(ktr + cb2 + (size_t)(16 * q2) * 2048 + 32);
        }
    };

    loadKQ(0); loadVB(0); loadT(0); loadA(0); loadKC(0);
    __syncthreads();

    for (int c = 0; c < NCH; ++c) {
        const int cn = (c + 1 < NCH) ? c + 1 : c;
        const int trow0 = b * 2048 + c * 64;

        // ---- phase A: W = K*(Shi+Slo); O1 = Q*(Shi+Slo) ----
        f32x4 Wacc = (f32x4){0.f, 0.f, 0.f, 0.f};
        f32x4 O1   = (f32x4){0.f, 0.f, 0.f, 0.f};
#pragma unroll
        for (int ks = 0; ks < 8; ++ks) {
            const int pb = (((ks * 4 + g4) ^ (vlow & 7)) << 3);
            bf16x8 bH = *(const bf16x8*)&Shi[vlow * 256 + pb];
            bf16x8 bL = *(const bf16x8*)&Slo[vlow * 256 + pb];
            Wacc = MFMA(kf[ks], bH, Wacc); Wacc = MFMA(kf[ks], bL, Wacc);
            O1   = MFMA(qf[ks], bH, O1);   O1   = MFMA(qf[ks], bL, O1);
        }
        // R = beta*(V - W) -> LDS hi/lo
        {
            const int tslot = 2 * w + (g4 >> 1);
            const int base = vlow * 64 + ((tslot ^ (vlow & 7)) << 3) + ((g4 & 1) << 2);
            u16t rh[4], rl[4];
#pragma unroll
            for (int rg = 0; rg < 4; ++rg) {
                float rv = bta[rg] * (bf2f(vfb[rg]) - Wacc[rg]);
                rh[rg] = f2bf(rv);
                rl[rg] = f2bf(rv - bf2f(rh[rg]));
            }
            uint2 ph, pl;
            ph.x = (u32t)rh[0] | ((u32t)rh[1] << 16); ph.y = (u32t)rh[2] | ((u32t)rh[3] << 16);
            pl.x = (u32t)rl[0] | ((u32t)rl[1] << 16); pl.y = (u32t)rl[2] | ((u32t)rl[3] << 16);
            *(uint2*)&Rhi[base] = ph;
            *(uint2*)&Rlo[base] = pl;
        }
        loadKQ(cn);      // kf/qf dead -> prefetch next chunk
        loadVB(cn);
        __syncthreads();

        // ---- phase B: U = (Thi+Tlo)*(Rhi+Rlo) ----
        f32x4 Uacc = (f32x4){0.f, 0.f, 0.f, 0.f};
#pragma unroll
        for (int ks = 0; ks < 2; ++ks) {
            const int pb = (((ks * 4 + g4) ^ (vlow & 7)) << 3);
            bf16x8 bH = *(const bf16x8*)&Rhi[vlow * 64 + pb];
            bf16x8 bL = *(const bf16x8*)&Rlo[vlow * 64 + pb];
            Uacc = MFMA(tfh[ks], bH, Uacc);
            Uacc = MFMA(tfh[ks], bL, Uacc);
            Uacc = MFMA(tfl[ks], bH, Uacc);
        }
        {
            const int tslot = 2 * w + (g4 >> 1);
            const int base = vlow * 64 + ((tslot ^ (vlow & 7)) << 3) + ((g4 & 1) << 2);
            u16t uh[4], ul[4];
#pragma unroll
            for (int rg = 0; rg < 4; ++rg) {
                uh[rg] = f2bf(Uacc[rg]);
                ul[rg] = f2bf(Uacc[rg] - bf2f(uh[rg]));
            }
            uint2 ph, pl;
            ph.x = (u32t)uh[0] | ((u32t)uh[1] << 16); ph.y = (u32t)uh[2] | ((u32t)uh[3] << 16);
            pl.x = (u32t)ul[0] | ((u32t)ul[1] << 16); pl.y = (u32t)ul[2] | ((u32t)ul[3] << 16);
            *(uint2*)&Uhi[base] = ph;
            *(uint2*)&Ulo[base] = pl;
        }
        loadT(cn);       // tf dead -> prefetch
        __syncthreads();

        // ---- phase C: O = O1 + A*U ; S += K^T*U ; refresh S mirror ----
        bf16x8 uhf[2], ulf[2];
#pragma unroll
        for (int ks = 0; ks < 2; ++ks) {
            const int pb = (((ks * 4 + g4) ^ (vlow & 7)) << 3);
            uhf[ks] = *(const bf16x8*)&Uhi[vlow * 64 + pb];
            ulf[ks] = *(const bf16x8*)&Ulo[vlow * 64 + pb];
        }
        f32x4 Oacc = O1;
#pragma unroll
        for (int ks = 0; ks < 2; ++ks) {
            Oacc = MFMA(af[ks], uhf[ks], Oacc);
            Oacc = MFMA(af[ks], ulf[ks], Oacc);
        }
#pragma unroll
        for (int rg = 0; rg < 4; ++rg)
            o_raw[(size_t)(trow0 + 16 * w + 4 * g4 + rg) * 1024 + h * 256 + vcol0 + vlow] = f2bf(Oacc[rg]);
        loadA(cn);       // af dead -> prefetch

#pragma unroll
        for (int q = 0; q < 4; ++q) {
#pragma unroll
            for (int ks = 0; ks < 2; ++ks) {
                sf[q] = MFMA(kcf[q * 2 + ks], uhf[ks], sf[q]);
                sf[q] = MFMA(kcf[q * 2 + ks], ulf[ks], sf[q]);
            }
        }
        loadKC(cn);      // kcf dead -> prefetch

        // S mirror refresh (hi/lo)
#pragma unroll
        for (int q = 0; q < 4; ++q) {
            u16t sh[4], sl[4];
#pragma unroll
            for (int rg = 0; rg < 4; ++rg) {
                u16t hi = f2bf(sf[q][rg]);
                sh[rg] = hi;
                sl[rg] = f2bf(sf[q][rg] - bf2f(hi));
            }
            const int rslot = 8 * w + 2 * q + (g4 >> 1);
            const int base = vlow * 256 + ((rslot ^ (vlow & 7)) << 3) + ((g4 & 1) << 2);
            uint2 ph, pl;
            ph.x = (u32t)sh[0] | ((u32t)sh[1] << 16); ph.y = (u32t)sh[2] | ((u32t)sh[3] << 16);
            pl.x = (u32t)sl[0] | ((u32t)sl[1] << 16); pl.y = (u32t)sl[2] | ((u32t)sl[3] << 16);
            *(uint2*)&Shi[base] = ph;
            *(uint2*)&Slo[base] = pl;
        }
        __syncthreads();
    }
}

// =================== rms_norm (bf16 in -> bf16 out) ======================
__global__ __launch_bounds__(256) void rms_kernel(const u16t* __restrict__ in,
                                                  const float* __restrict__ w,
                                                  u16t* __restrict__ out) {
    const int gw   = (blockIdx.x * blockDim.x + threadIdx.x) >> 6;
    const int lane = threadIdx.x & 63;
    const int r = gw >> 2;
    const int h = gw & 3;
    const size_t base = (size_t)r * HIDD + h * 256 + lane * 4;
    ushort4 xv = *(const ushort4*)&in[base];
    float x0 = bf2f(xv.x), x1 = bf2f(xv.y), x2 = bf2f(xv.z), x3 = bf2f(xv.w);
    float ss = x0 * x0 + x1 * x1 + x2 * x2 + x3 * x3;
    ss = waveReduceSum(ss);
    const float sc = rsqrtf(ss * (1.0f / 256.0f) + 1e-5f);
    float4 wv = *(const float4*)&w[lane * 4];
    ushort4 o;
    o.x = f2bf(x0 * sc * wv.x); o.y = f2bf(x1 * sc * wv.y);
    o.z = f2bf(x2 * sc * wv.z); o.w = f2bf(x3 * sc * wv.w);
    *(ushort4*)&out[base] = o;
}

extern "C" void kernel_launch(void* const* d_in, const int* in_sizes, int n_in,
                              void* d_out, int out_size, void* d_ws, size_t ws_size,
                              hipStream_t stream) {
    const float* X      = (const float*)d_in[0];
    const float* Wq     = (const float*)d_in[1];
    const float* Wk     = (const float*)d_in[2];
    const float* Wv     = (const float*)d_in[3];
    const float* Wb     = (const float*)d_in[4];
    const float* conv_q = (const float*)d_in[5];
    const float* conv_k = (const float*)d_in[6];
    const float* conv_v = (const float*)d_in[7];
    const float* norm_w = (const float*)d_in[8];
    const float* Wo     = (const float*)d_in[9];
    float* out = (float*)d_out;

    char* W8 = (char*)d_ws;
    const size_t MB = 1u << 20;
    u16t* Xbf   = (u16t*)(W8 + 0 * MB);    // -> o_raw after projections
    u16t* o_raw = Xbf;
    u16t* qpre  = (u16t*)(W8 + 8 * MB);    // -> o_nrm after conv_q
    u16t* o_nrm = qpre;
    u16t* kpre  = (u16t*)(W8 + 16 * MB);   // -> Tghi/Tglo/Agb after conv_k
    u16t* Tghi  = (u16t*)(W8 + 16 * MB);
    u16t* Tglo  = (u16t*)(W8 + 18 * MB);
    u16t* Agb   = (u16t*)(W8 + 20 * MB);
    u16t* vpre  = (u16t*)(W8 + 24 * MB);   // -> ktr after conv_v
    u16t* ktr   = (u16t*)(W8 + 24 * MB);
    u16t* WqT   = (u16t*)(W8 + 32 * MB);   // -> qcb after QKV gemm
    u16t* qcb   = (u16t*)(W8 + 32 * MB);
    u16t* WkT   = (u16t*)(W8 + 40 * MB);   // -> kcb
    u16t* kcb   = (u16t*)(W8 + 40 * MB);
    u16t* WvT   = (u16t*)(W8 + 48 * MB);   // -> vcb
    u16t* vcb   = (u16t*)(W8 + 48 * MB);
    u16t* WoT   = (u16t*)(W8 + 56 * MB);
    float* betab = (float*)(W8 + 58 * MB);

    const size_t PL = 4194304;   // 8 MB plane stride in u16 elements

    dim3 tgrid(16, 16);
    f2bf_kernel<<<2048, 256, 0, stream>>>(X, Xbf);
    transpose_w<<<tgrid, 256, 0, stream>>>(Wq, WqT);
    transpose_w<<<tgrid, 256, 0, stream>>>(Wk, WkT);
    transpose_w<<<tgrid, 256, 0, stream>>>(Wv, WvT);
    transpose_w<<<tgrid, 256, 0, stream>>>(Wo, WoT);

    // fused QKV projection: N = 3072, plane-strided B (WqT/WkT/WvT) and C (q/k/vpre)
    gemm_mfma<<<dim3(24, 32), 256, 0, stream>>>(Xbf, WqT, nullptr, qpre, 1,
                                                ROWS, 3072, HIDD, PL, PL);
    beta_kernel<<<ROWS / 4, 256, 0, stream>>>(X, Wb, betab);

    conv_bf16<<<ROWS, 256, 0, stream>>>(vpre, conv_v, vcb, 0);      // frees vpre
    conv_bf16<<<ROWS, 256, 0, stream>>>(qpre, conv_q, qcb, 1);
    conv_k_chunk<<<256, 256, 0, stream>>>(kpre, conv_k, kcb, ktr);  // ktr over vpre

    prep_kernel<<<256, 256, 0, stream>>>(qcb, kcb, betab, Tghi, Tglo, Agb);
    scan_mfma<<<128, 256, 0, stream>>>(qcb, kcb, ktr, vcb, betab, Tghi, Tglo, Agb, o_raw);

    rms_kernel<<<ROWS, 256, 0, stream>>>(o_raw, norm_w, o_nrm);
    gemm_mfma<<<dim3(8, 32), 256, 0, stream>>>(o_nrm, WoT, out, nullptr, 0,
                                               ROWS, HIDD, HIDD, 0, 0);
}

// Round 5
// 286.672 us; speedup vs baseline: 6.3642x; 1.0253x over previous
//
#include <hip/hip_runtime.h>
#include <math.h>

#define BB   2
#define SS   2048
#define HIDD 1024
#define ROWS 4096
#define NCH  32
#define CH   64

typedef unsigned short u16t;
typedef unsigned int   u32t;

typedef __attribute__((ext_vector_type(8))) short bf16x8;
typedef __attribute__((ext_vector_type(4))) float f32x4;

__device__ __forceinline__ float bf2f(u16t u) { return __uint_as_float(((u32t)u) << 16); }
__device__ __forceinline__ u16t f2bf(float f) {
    u32t b = __float_as_uint(f);
    return (u16t)((b + 0x7FFFu + ((b >> 16) & 1u)) >> 16);
}
__device__ __forceinline__ float lo_bf(u32t u) { return __uint_as_float(u << 16); }
__device__ __forceinline__ float hi_bf(u32t u) { return __uint_as_float(u & 0xFFFF0000u); }

__device__ __forceinline__ float waveReduceSum(float v) {
#pragma unroll
    for (int m = 1; m < 64; m <<= 1) v += __shfl_xor(v, m, 64);
    return v;
}

__device__ __forceinline__ void gload16(const void* g, void* l) {
    __builtin_amdgcn_global_load_lds(
        (const __attribute__((address_space(1))) unsigned int*)g,
        (__attribute__((address_space(3))) unsigned int*)l, 16, 0, 0);
}

#define MFMA(a, b, c) __builtin_amdgcn_mfma_f32_16x16x32_bf16(a, b, c, 0, 0, 0)

// =================== X f32 -> bf16 ======================================
__global__ __launch_bounds__(256) void f2bf_kernel(const float* __restrict__ in,
                                                   u16t* __restrict__ out) {
    const size_t idx = ((size_t)blockIdx.x * 256 + threadIdx.x) * 8;
    float4 a = *(const float4*)&in[idx];
    float4 b = *(const float4*)&in[idx + 4];
    ushort4 o1, o2;
    o1.x = f2bf(a.x); o1.y = f2bf(a.y); o1.z = f2bf(a.z); o1.w = f2bf(a.w);
    o2.x = f2bf(b.x); o2.y = f2bf(b.y); o2.z = f2bf(b.z); o2.w = f2bf(b.w);
    *(ushort4*)&out[idx] = o1;
    *(ushort4*)&out[idx + 4] = o2;
}

// ====== 4 weight transposes fused in one launch (blockIdx.z selects) ======
__global__ __launch_bounds__(256) void transpose_w4(const float* __restrict__ W0,
                                                    const float* __restrict__ W1,
                                                    const float* __restrict__ W2,
                                                    const float* __restrict__ W3,
                                                    u16t* __restrict__ T0,
                                                    u16t* __restrict__ T1,
                                                    u16t* __restrict__ T2,
                                                    u16t* __restrict__ T3) {
    __shared__ u16t tile[64][65];
    const int z = blockIdx.z;
    const float* W = (z == 0) ? W0 : (z == 1) ? W1 : (z == 2) ? W2 : W3;
    u16t* WT = (z == 0) ? T0 : (z == 1) ? T1 : (z == 2) ? T2 : T3;
    const int t = threadIdx.x;
    const int r0 = blockIdx.y * 64, c0 = blockIdx.x * 64;
    const int lr = t >> 2, lc4 = (t & 3) * 16;
#pragma unroll
    for (int m = 0; m < 4; ++m) {
        float4 v = *(const float4*)&W[(size_t)(r0 + lr) * 1024 + c0 + lc4 + m * 4];
        tile[lr][lc4 + m * 4 + 0] = f2bf(v.x);
        tile[lr][lc4 + m * 4 + 1] = f2bf(v.y);
        tile[lr][lc4 + m * 4 + 2] = f2bf(v.z);
        tile[lr][lc4 + m * 4 + 3] = f2bf(v.w);
    }
    __syncthreads();
#pragma unroll
    for (int m = 0; m < 16; ++m)
        WT[(size_t)(c0 + lr) * 1024 + r0 + lc4 + m] = tile[lc4 + m][lr];
}

// ======= MFMA GEMM: C[M,N] = A[M,K] * BT[N,K]^T, plane-strided B/C =======
__global__ __launch_bounds__(256) void gemm_mfma(const u16t* __restrict__ A,
                                                 const u16t* __restrict__ BT,
                                                 float* __restrict__ Cf,
                                                 u16t* __restrict__ Cb, int obf,
                                                 int M, int N, int K,
                                                 size_t bStrideP, size_t cStrideP) {
    __shared__ u16t As[128 * 64];
    __shared__ u16t Bs[128 * 64];
    const int t = threadIdx.x, l = t & 63, w = t >> 6;
    const int wr = w >> 1, wc = w & 1;
    const int rowBase = blockIdx.y * 128, colBase = blockIdx.x * 128;
    const int l15 = l & 15, g4 = l >> 4;

    const int bplane = colBase >> 10;
    const int bcol = colBase & 1023;

    const int srow = l >> 3;
    const int sj = (l & 7) ^ srow;
    const u16t* aSrc = A + (size_t)(rowBase + srow) * K + sj * 8;
    const u16t* bSrc = BT + (size_t)bplane * bStrideP + (size_t)(bcol + srow) * K + sj * 8;

    f32x4 acc[4][4];
#pragma unroll
    for (int i = 0; i < 4; ++i)
#pragma unroll
        for (int j = 0; j < 4; ++j) acc[i][j] = (f32x4){0.f, 0.f, 0.f, 0.f};

    for (int k0 = 0; k0 < K; k0 += 64) {
#pragma unroll
        for (int i = 0; i < 4; ++i) {
            const int rb = (i * 4 + w) * 8;
            gload16(aSrc + (size_t)rb * K + k0, &As[rb * 64]);
            gload16(bSrc + (size_t)rb * K + k0, &Bs[rb * 64]);
        }
        __syncthreads();
#pragma unroll
        for (int kh = 0; kh < 2; ++kh) {
            bf16x8 aF[4], bF[4];
#pragma unroll
            for (int mi = 0; mi < 4; ++mi) {
                const int row = wr * 64 + mi * 16 + l15;
                const int phys = (kh * 4 + g4) ^ (row & 7);
                aF[mi] = *(const bf16x8*)&As[row * 64 + phys * 8];
            }
#pragma unroll
            for (int ni = 0; ni < 4; ++ni) {
                const int row = wc * 64 + ni * 16 + l15;
                const int phys = (kh * 4 + g4) ^ (row & 7);
                bF[ni] = *(const bf16x8*)&Bs[row * 64 + phys * 8];
            }
#pragma unroll
            for (int mi = 0; mi < 4; ++mi)
#pragma unroll
                for (int ni = 0; ni < 4; ++ni)
                    acc[mi][ni] = MFMA(aF[mi], bF[ni], acc[mi][ni]);
        }
        __syncthreads();
    }
#pragma unroll
    for (int mi = 0; mi < 4; ++mi)
#pragma unroll
        for (int ni = 0; ni < 4; ++ni)
#pragma unroll
            for (int rg = 0; rg < 4; ++rg) {
                const int row = rowBase + wr * 64 + mi * 16 + g4 * 4 + rg;
                const int col = colBase + wc * 64 + ni * 16 + l15;
                const int plane = col >> 10, cc = col & 1023;
                const float v = acc[mi][ni][rg];
                if (obf) Cb[(size_t)plane * cStrideP + (size_t)row * 1024 + cc] = f2bf(v);
                else     Cf[(size_t)plane * cStrideP + (size_t)row * 1024 + cc] = v;
            }
}

// =================== beta = sigmoid(X @ Wb) ==============================
__global__ __launch_bounds__(256) void beta_kernel(const float* __restrict__ X,
                                                   const float* __restrict__ Wb,
                                                   float* __restrict__ beta) {
    const int gw   = (blockIdx.x * blockDim.x + threadIdx.x) >> 6;
    const int lane = threadIdx.x & 63;
    if (gw >= ROWS) return;
    const float* x = X + (size_t)gw * HIDD;
    float a0 = 0.f, a1 = 0.f, a2 = 0.f, a3 = 0.f;
#pragma unroll
    for (int i = 0; i < 4; ++i) {
        const int k = lane * 16 + i * 4;
        float4 xv = *(const float4*)&x[k];
        float4 w0 = *(const float4*)&Wb[(size_t)(k + 0) * 4];
        float4 w1 = *(const float4*)&Wb[(size_t)(k + 1) * 4];
        float4 w2 = *(const float4*)&Wb[(size_t)(k + 2) * 4];
        float4 w3 = *(const float4*)&Wb[(size_t)(k + 3) * 4];
        a0 += xv.x * w0.x + xv.y * w1.x + xv.z * w2.x + xv.w * w3.x;
        a1 += xv.x * w0.y + xv.y * w1.y + xv.z * w2.y + xv.w * w3.y;
        a2 += xv.x * w0.z + xv.y * w1.z + xv.z * w2.z + xv.w * w3.z;
        a3 += xv.x * w0.w + xv.y * w1.w + xv.z * w2.w + xv.w * w3.w;
    }
    a0 = waveReduceSum(a0); a1 = waveReduceSum(a1);
    a2 = waveReduceSum(a2); a3 = waveReduceSum(a3);
    if (lane == 0) {
        float4 o = make_float4(1.f / (1.f + expf(-a0)), 1.f / (1.f + expf(-a1)),
                               1.f / (1.f + expf(-a2)), 1.f / (1.f + expf(-a3)));
        *(float4*)&beta[(size_t)gw * 4] = o;
    }
}

// == causal conv(K=4)+silu(+l2norm), q & v fused in one launch (blockIdx.y) ==
__global__ __launch_bounds__(256) void conv_qv(const u16t* __restrict__ inQ,
                                               const float* __restrict__ wQ,
                                               u16t* __restrict__ outQ,
                                               const u16t* __restrict__ inV,
                                               const float* __restrict__ wV,
                                               u16t* __restrict__ outV) {
    const int isQ = (blockIdx.y == 0);
    const u16t* in = isQ ? inQ : inV;
    const float* w = isQ ? wQ : wV;
    u16t* out      = isQ ? outQ : outV;
    const int doL2 = isQ;

    const int gw   = (blockIdx.x * blockDim.x + threadIdx.x) >> 6;
    const int lane = threadIdx.x & 63;
    const int r = gw >> 2;
    const int h = gw & 3;
    const int b = r >> 11;
    const int s = r & 2047;
    const int c4 = h * 256 + lane * 4;

    const float4 wr0 = *(const float4*)&w[(size_t)(c4 + 0) * 4];
    const float4 wr1 = *(const float4*)&w[(size_t)(c4 + 1) * 4];
    const float4 wr2 = *(const float4*)&w[(size_t)(c4 + 2) * 4];
    const float4 wr3 = *(const float4*)&w[(size_t)(c4 + 3) * 4];

    const size_t rowB = (size_t)(b << 11);
    float x0[4] = {0, 0, 0, 0}, x1[4] = {0, 0, 0, 0}, x2[4] = {0, 0, 0, 0}, x3[4];
    ushort4 u;
    if (s >= 3) { u = *(const ushort4*)&in[(rowB + s - 3) * HIDD + c4];
        x0[0] = bf2f(u.x); x0[1] = bf2f(u.y); x0[2] = bf2f(u.z); x0[3] = bf2f(u.w); }
    if (s >= 2) { u = *(const ushort4*)&in[(rowB + s - 2) * HIDD + c4];
        x1[0] = bf2f(u.x); x1[1] = bf2f(u.y); x1[2] = bf2f(u.z); x1[3] = bf2f(u.w); }
    if (s >= 1) { u = *(const ushort4*)&in[(rowB + s - 1) * HIDD + c4];
        x2[0] = bf2f(u.x); x2[1] = bf2f(u.y); x2[2] = bf2f(u.z); x2[3] = bf2f(u.w); }
    u = *(const ushort4*)&in[(rowB + s) * HIDD + c4];
    x3[0] = bf2f(u.x); x3[1] = bf2f(u.y); x3[2] = bf2f(u.z); x3[3] = bf2f(u.w);

    float y0 = wr0.x * x0[0] + wr0.y * x1[0] + wr0.z * x2[0] + wr0.w * x3[0];
    float y1 = wr1.x * x0[1] + wr1.y * x1[1] + wr1.z * x2[1] + wr1.w * x3[1];
    float y2 = wr2.x * x0[2] + wr2.y * x1[2] + wr2.z * x2[2] + wr2.w * x3[2];
    float y3 = wr3.x * x0[3] + wr3.y * x1[3] + wr3.z * x2[3] + wr3.w * x3[3];

    y0 = y0 / (1.f + expf(-y0)); y1 = y1 / (1.f + expf(-y1));
    y2 = y2 / (1.f + expf(-y2)); y3 = y3 / (1.f + expf(-y3));

    if (doL2) {
        float ss = y0 * y0 + y1 * y1 + y2 * y2 + y3 * y3;
        ss = waveReduceSum(ss);
        float sc = rsqrtf(ss + 1e-6f);
        y0 *= sc; y1 *= sc; y2 *= sc; y3 *= sc;
    }
    ushort4 o;
    o.x = f2bf(y0); o.y = f2bf(y1); o.z = f2bf(y2); o.w = f2bf(y3);
    *(ushort4*)&out[(size_t)r * HIDD + c4] = o;
}

// ====== conv for K: row-major out + transposed ktr[bh*256+r][t] ==========
__global__ __launch_bounds__(256) void conv_k_chunk(const u16t* __restrict__ pre,
                                                    const float* __restrict__ w,
                                                    u16t* __restrict__ rowout,
                                                    u16t* __restrict__ trout) {
    const int t = threadIdx.x;
    const int bh = blockIdx.x >> 5, c = blockIdx.x & 31;
    const int b = bh >> 2, h = bh & 3;
    const int i = t >> 2, g = t & 3;
    const int s = c * 64 + i;
    const size_t row = (size_t)b * 2048 + s;
    const int ch0 = h * 256 + g * 64;
    const int cloc = g * 64;
    float y[64];
#pragma unroll
    for (int m = 0; m < 8; ++m) {
        const int cm = ch0 + m * 8;
        uint4 x3 = *(const uint4*)&pre[row * 1024 + cm];
        uint4 x2 = (s >= 1) ? *(const uint4*)&pre[(row - 1) * 1024 + cm] : make_uint4(0, 0, 0, 0);
        uint4 x1 = (s >= 2) ? *(const uint4*)&pre[(row - 2) * 1024 + cm] : make_uint4(0, 0, 0, 0);
        uint4 x0 = (s >= 3) ? *(const uint4*)&pre[(row - 3) * 1024 + cm] : make_uint4(0, 0, 0, 0);
        u32t c0[4] = {x0.x, x0.y, x0.z, x0.w};
        u32t c1[4] = {x1.x, x1.y, x1.z, x1.w};
        u32t c2[4] = {x2.x, x2.y, x2.z, x2.w};
        u32t c3[4] = {x3.x, x3.y, x3.z, x3.w};
#pragma unroll
        for (int p = 0; p < 4; ++p) {
            const int ch = m * 8 + p * 2;
            float4 wA = *(const float4*)&w[(size_t)(ch0 + ch) * 4];
            float4 wB = *(const float4*)&w[(size_t)(ch0 + ch + 1) * 4];
            float ya = wA.x * lo_bf(c0[p]) + wA.y * lo_bf(c1[p]) + wA.z * lo_bf(c2[p]) + wA.w * lo_bf(c3[p]);
            float yb = wB.x * hi_bf(c0[p]) + wB.y * hi_bf(c1[p]) + wB.z * hi_bf(c2[p]) + wB.w * hi_bf(c3[p]);
            ya = ya / (1.f + expf(-ya));
            yb = yb / (1.f + expf(-yb));
            y[ch] = ya; y[ch + 1] = yb;
        }
    }
    float ss = 0.f;
#pragma unroll
    for (int e = 0; e < 64; ++e) ss += y[e] * y[e];
    ss += __shfl_xor(ss, 1);
    ss += __shfl_xor(ss, 2);
    const float sc = rsqrtf(ss + 1e-6f);
#pragma unroll
    for (int m = 0; m < 8; ++m) {
        uint4 o;
        u32t* op = (u32t*)&o;
#pragma unroll
        for (int p = 0; p < 4; ++p) {
            u16t a = f2bf(y[m * 8 + p * 2] * sc);
            u16t bb2 = f2bf(y[m * 8 + p * 2 + 1] * sc);
            op[p] = (u32t)a | ((u32t)bb2 << 16);
        }
        *(uint4*)&rowout[row * 1024 + ch0 + m * 8] = o;
    }
#pragma unroll
    for (int e = 0; e < 64; ++e)
        trout[((size_t)bh * 256 + cloc + e) * 2048 + s] = f2bf(y[e] * sc);
}

// ====== prep: per chunk T=(I+strict_lower(diag(b)KK^T))^-1 (bf16 hi/lo) ===
__global__ __launch_bounds__(256) void prep_kernel(const u16t* __restrict__ qcb,
                                                   const u16t* __restrict__ kcb,
                                                   const float* __restrict__ beta,
                                                   u16t* __restrict__ Tghi,
                                                   u16t* __restrict__ Tglo,
                                                   u16t* __restrict__ Agb) {
    __shared__ float KT[256][68];
    __shared__ float QT[256][68];
    __shared__ float Af[64][68];
    const int t = threadIdx.x;
    const int bhc = blockIdx.x;
    const int bh = bhc >> 5, c = bhc & 31;
    const int b = bh >> 2, h = bh & 3;
    const int tb = b * SS + c * CH;

    {
        const int i = t & 63, rb = t >> 6;
        const u16t* kg = kcb + (size_t)(tb + i) * HIDD + h * 256 + rb * 64;
        const u16t* qg = qcb + (size_t)(tb + i) * HIDD + h * 256 + rb * 64;
#pragma unroll
        for (int m = 0; m < 8; ++m) {
            uint4 kv = ((const uint4*)kg)[m];
            uint4 qv = ((const uint4*)qg)[m];
            u32t kw[4] = {kv.x, kv.y, kv.z, kv.w};
            u32t qw[4] = {qv.x, qv.y, qv.z, qv.w};
#pragma unroll
            for (int n = 0; n < 4; ++n) {
                int rr = rb * 64 + m * 8 + n * 2;
                KT[rr][i]     = lo_bf(kw[n]);
                KT[rr + 1][i] = hi_bf(kw[n]);
                QT[rr][i]     = lo_bf(qw[n]);
                QT[rr + 1][i] = hi_bf(qw[n]);
            }
        }
    }
    __syncthreads();

    const int it = t & 63, jb = t >> 6;
    float kk[16], qk[16];
#pragma unroll
    for (int m = 0; m < 16; ++m) { kk[m] = 0.f; qk[m] = 0.f; }
#pragma unroll 2
    for (int r = 0; r < 256; ++r) {
        float ki = KT[r][it];
        float qi = QT[r][it];
        float4 ka = *(const float4*)&KT[r][jb * 16 + 0];
        float4 kb = *(const float4*)&KT[r][jb * 16 + 4];
        float4 kc = *(const float4*)&KT[r][jb * 16 + 8];
        float4 kd = *(const float4*)&KT[r][jb * 16 + 12];
        float kj[16] = {ka.x, ka.y, ka.z, ka.w, kb.x, kb.y, kb.z, kb.w,
                        kc.x, kc.y, kc.z, kc.w, kd.x, kd.y, kd.z, kd.w};
#pragma unroll
        for (int m = 0; m < 16; ++m) { kk[m] += ki * kj[m]; qk[m] += qi * kj[m]; }
    }

    const float bta = beta[(size_t)(tb + it) * 4 + h];
    u16t* ag = Agb + (size_t)bhc * 4096 + (size_t)it * 64 + jb * 16;
#pragma unroll
    for (int m = 0; m < 16; ++m) {
        int j = jb * 16 + m;
        Af[it][j] = (j < it) ? bta * kk[m] : 0.f;
    }
#pragma unroll
    for (int m4 = 0; m4 < 4; ++m4) {
        ushort4 o;
        o.x = f2bf((jb * 16 + m4 * 4 + 0 <= it) ? qk[m4 * 4 + 0] : 0.f);
        o.y = f2bf((jb * 16 + m4 * 4 + 1 <= it) ? qk[m4 * 4 + 1] : 0.f);
        o.z = f2bf((jb * 16 + m4 * 4 + 2 <= it) ? qk[m4 * 4 + 2] : 0.f);
        o.w = f2bf((jb * 16 + m4 * 4 + 3 <= it) ? qk[m4 * 4 + 3] : 0.f);
        *(ushort4*)&ag[m4 * 4] = o;
    }
    __syncthreads();

    if (t < 64) {
        const int ccol = t;
        float tc[64];
#pragma unroll
        for (int j = 0; j < 64; ++j) tc[j] = (j == ccol) ? 1.f : 0.f;
#pragma unroll
        for (int i = 1; i < 64; ++i) {
            float a = 0.f;
#pragma unroll
            for (int j = 0; j < i; ++j) a += Af[i][j] * tc[j];
            tc[i] -= a;
        }
        u16t* th = Tghi + (size_t)bhc * 4096;
        u16t* tl = Tglo + (size_t)bhc * 4096;
#pragma unroll
        for (int i = 0; i < 64; ++i) {
            u16t hi = f2bf(tc[i]);
            th[i * 64 + ccol] = hi;
            tl[i * 64 + ccol] = f2bf(tc[i] - bf2f(hi));
        }
    }
}

// ====== MFMA scan v3: XCD-affinity swizzle (all v-tiles of a bh share L2) ==
__global__ __launch_bounds__(256, 1) void scan_mfma(const u16t* __restrict__ qcb,
                                                    const u16t* __restrict__ kcb,
                                                    const u16t* __restrict__ ktr,
                                                    const u16t* __restrict__ vcb,
                                                    const float* __restrict__ beta,
                                                    const u16t* __restrict__ TghiG,
                                                    const u16t* __restrict__ TgloG,
                                                    const u16t* __restrict__ AgbG,
                                                    u16t* __restrict__ o_raw) {
    __shared__ u16t Shi[16 * 256];  // [v][r] slot-XOR swizzled
    __shared__ u16t Slo[16 * 256];
    __shared__ u16t Rhi[16 * 64];   // [v][t] slot-XOR swizzled
    __shared__ u16t Rlo[16 * 64];
    __shared__ u16t Uhi[16 * 64];
    __shared__ u16t Ulo[16 * 64];

    const int t = threadIdx.x, l = t & 63, w = t >> 6;
    // XCD-affinity: dispatch round-robins XCD on blockIdx%8 -> pin bh to one XCD
    const int bh = blockIdx.x & 7, vt = blockIdx.x >> 3;
    const int b = bh >> 2, h = bh & 3;
    const int vcol0 = vt * 16;
    const int vlow = l & 15, g4 = l >> 4;

    for (int i = t; i < 16 * 256; i += 256) { Shi[i] = 0; Slo[i] = 0; }
    f32x4 sf[4];
#pragma unroll
    for (int q = 0; q < 4; ++q) sf[q] = (f32x4){0.f, 0.f, 0.f, 0.f};

    bf16x8 kf[8], qf[8], tfh[2], tfl[2], af[2], kcf[8];
    u16t vfb[4];
    float bta[4];

    auto loadKQ = [&](int c) {
        const size_t rb = (size_t)(b * 2048 + c * 64 + 16 * w + vlow) * 1024 + h * 256 + g4 * 8;
#pragma unroll
        for (int ks = 0; ks < 8; ++ks) {
            kf[ks] = *(const bf16x8*)(kcb + rb + ks * 32);
            qf[ks] = *(const bf16x8*)(qcb + rb + ks * 32);
        }
    };
    auto loadVB = [&](int c) {
        const int r0 = b * 2048 + c * 64 + 16 * w + 4 * g4;
#pragma unroll
        for (int rg = 0; rg < 4; ++rg) {
            vfb[rg] = vcb[(size_t)(r0 + rg) * 1024 + h * 256 + vcol0 + vlow];
            bta[rg] = beta[(size_t)(r0 + rg) * 4 + h];
        }
    };
    auto loadT = [&](int c) {
        const size_t tb2 = (size_t)(bh * 32 + c) * 4096 + (size_t)(16 * w + vlow) * 64 + g4 * 8;
        tfh[0] = *(const bf16x8*)(TghiG + tb2);
        tfh[1] = *(const bf16x8*)(TghiG + tb2 + 32);
        tfl[0] = *(const bf16x8*)(TgloG + tb2);
        tfl[1] = *(const bf16x8*)(TgloG + tb2 + 32);
    };
    auto loadA = [&](int c) {
        const size_t tb2 = (size_t)(bh * 32 + c) * 4096 + (size_t)(16 * w + vlow) * 64 + g4 * 8;
        af[0] = *(const bf16x8*)(AgbG + tb2);
        af[1] = *(const bf16x8*)(AgbG + tb2 + 32);
    };
    auto loadKC = [&](int c) {
        const size_t cb2 = ((size_t)bh * 256 + 64 * w + vlow) * 2048 + c * 64 + g4 * 8;
#pragma unroll
        for (int q2 = 0; q2 < 4; ++q2) {
            kcf[q2 * 2 + 0] = *(const bf16x8*)(ktr + cb2 + (size_t)(16 * q2) * 2048);
            kcf[q2 * 2 + 1] = *(const bf16x8*)(ktr + cb2 + (size_t)(16 * q2) * 2048 + 32);
        }
    };

    loadKQ(0); loadVB(0); loadT(0); loadA(0); loadKC(0);
    __syncthreads();

    for (int c = 0; c < NCH; ++c) {
        const int cn = (c + 1 < NCH) ? c + 1 : c;
        const int trow0 = b * 2048 + c * 64;

        // ---- phase A: W = K*(Shi+Slo); O1 = Q*(Shi+Slo) ----
        f32x4 Wacc = (f32x4){0.f, 0.f, 0.f, 0.f};
        f32x4 O1   = (f32x4){0.f, 0.f, 0.f, 0.f};
#pragma unroll
        for (int ks = 0; ks < 8; ++ks) {
            const int pb = (((ks * 4 + g4) ^ (vlow & 7)) << 3);
            bf16x8 bH = *(const bf16x8*)&Shi[vlow * 256 + pb];
            bf16x8 bL = *(const bf16x8*)&Slo[vlow * 256 + pb];
            Wacc = MFMA(kf[ks], bH, Wacc); Wacc = MFMA(kf[ks], bL, Wacc);
            O1   = MFMA(qf[ks], bH, O1);   O1   = MFMA(qf[ks], bL, O1);
        }
        // R = beta*(V - W) -> LDS hi/lo
        {
            const int tslot = 2 * w + (g4 >> 1);
            const int base = vlow * 64 + ((tslot ^ (vlow & 7)) << 3) + ((g4 & 1) << 2);
            u16t rh[4], rl[4];
#pragma unroll
            for (int rg = 0; rg < 4; ++rg) {
                float rv = bta[rg] * (bf2f(vfb[rg]) - Wacc[rg]);
                rh[rg] = f2bf(rv);
                rl[rg] = f2bf(rv - bf2f(rh[rg]));
            }
            uint2 ph, pl;
            ph.x = (u32t)rh[0] | ((u32t)rh[1] << 16); ph.y = (u32t)rh[2] | ((u32t)rh[3] << 16);
            pl.x = (u32t)rl[0] | ((u32t)rl[1] << 16); pl.y = (u32t)rl[2] | ((u32t)rl[3] << 16);
            *(uint2*)&Rhi[base] = ph;
            *(uint2*)&Rlo[base] = pl;
        }
        loadKQ(cn);
        loadVB(cn);
        __syncthreads();

        // ---- phase B: U = (Thi+Tlo)*(Rhi+Rlo) ----
        f32x4 Uacc = (f32x4){0.f, 0.f, 0.f, 0.f};
#pragma unroll
        for (int ks = 0; ks < 2; ++ks) {
            const int pb = (((ks * 4 + g4) ^ (vlow & 7)) << 3);
            bf16x8 bH = *(const bf16x8*)&Rhi[vlow * 64 + pb];
            bf16x8 bL = *(const bf16x8*)&Rlo[vlow * 64 + pb];
            Uacc = MFMA(tfh[ks], bH, Uacc);
            Uacc = MFMA(tfh[ks], bL, Uacc);
            Uacc = MFMA(tfl[ks], bH, Uacc);
        }
        {
            const int tslot = 2 * w + (g4 >> 1);
            const int base = vlow * 64 + ((tslot ^ (vlow & 7)) << 3) + ((g4 & 1) << 2);
            u16t uh[4], ul[4];
#pragma unroll
            for (int rg = 0; rg < 4; ++rg) {
                uh[rg] = f2bf(Uacc[rg]);
                ul[rg] = f2bf(Uacc[rg] - bf2f(uh[rg]));
            }
            uint2 ph, pl;
            ph.x = (u32t)uh[0] | ((u32t)uh[1] << 16); ph.y = (u32t)uh[2] | ((u32t)uh[3] << 16);
            pl.x = (u32t)ul[0] | ((u32t)ul[1] << 16); pl.y = (u32t)ul[2] | ((u32t)ul[3] << 16);
            *(uint2*)&Uhi[base] = ph;
            *(uint2*)&Ulo[base] = pl;
        }
        loadT(cn);
        __syncthreads();

        // ---- phase C: O = O1 + A*U ; S += K^T*U ; refresh S mirror ----
        bf16x8 uhf[2], ulf[2];
#pragma unroll
        for (int ks = 0; ks < 2; ++ks) {
            const int pb = (((ks * 4 + g4) ^ (vlow & 7)) << 3);
            uhf[ks] = *(const bf16x8*)&Uhi[vlow * 64 + pb];
            ulf[ks] = *(const bf16x8*)&Ulo[vlow * 64 + pb];
        }
        f32x4 Oacc = O1;
#pragma unroll
        for (int ks = 0; ks < 2; ++ks) {
            Oacc = MFMA(af[ks], uhf[ks], Oacc);
            Oacc = MFMA(af[ks], ulf[ks], Oacc);
        }
#pragma unroll
        for (int rg = 0; rg < 4; ++rg)
            o_raw[(size_t)(trow0 + 16 * w + 4 * g4 + rg) * 1024 + h * 256 + vcol0 + vlow] = f2bf(Oacc[rg]);
        loadA(cn);

#pragma unroll
        for (int q = 0; q < 4; ++q) {
#pragma unroll
            for (int ks = 0; ks < 2; ++ks) {
                sf[q] = MFMA(kcf[q * 2 + ks], uhf[ks], sf[q]);
                sf[q] = MFMA(kcf[q * 2 + ks], ulf[ks], sf[q]);
            }
        }
        loadKC(cn);

        // S mirror refresh (hi/lo)
#pragma unroll
        for (int q = 0; q < 4; ++q) {
            u16t sh[4], sl[4];
#pragma unroll
            for (int rg = 0; rg < 4; ++rg) {
                u16t hi = f2bf(sf[q][rg]);
                sh[rg] = hi;
                sl[rg] = f2bf(sf[q][rg] - bf2f(hi));
            }
            const int rslot = 8 * w + 2 * q + (g4 >> 1);
            const int base = vlow * 256 + ((rslot ^ (vlow & 7)) << 3) + ((g4 & 1) << 2);
            uint2 ph, pl;
            ph.x = (u32t)sh[0] | ((u32t)sh[1] << 16); ph.y = (u32t)sh[2] | ((u32t)sh[3] << 16);
            pl.x = (u32t)sl[0] | ((u32t)sl[1] << 16); pl.y = (u32t)sl[2] | ((u32t)sl[3] << 16);
            *(uint2*)&Shi[base] = ph;
            *(uint2*)&Slo[base] = pl;
        }
        __syncthreads();
    }
}

// =================== rms_norm (bf16 in -> bf16 out) ======================
__global__ __launch_bounds__(256) void rms_kernel(const u16t* __restrict__ in,
                                                  const float* __restrict__ w,
                                                  u16t* __restrict__ out) {
    const int gw   = (blockIdx.x * blockDim.x + threadIdx.x) >> 6;
    const int lane = threadIdx.x & 63;
    const int r = gw >> 2;
    const int h = gw & 3;
    const size_t base = (size_t)r * HIDD + h * 256 + lane * 4;
    ushort4 xv = *(const ushort4*)&in[base];
    float x0 = bf2f(xv.x), x1 = bf2f(xv.y), x2 = bf2f(xv.z), x3 = bf2f(xv.w);
    float ss = x0 * x0 + x1 * x1 + x2 * x2 + x3 * x3;
    ss = waveReduceSum(ss);
    const float sc = rsqrtf(ss * (1.0f / 256.0f) + 1e-5f);
    float4 wv = *(const float4*)&w[lane * 4];
    ushort4 o;
    o.x = f2bf(x0 * sc * wv.x); o.y = f2bf(x1 * sc * wv.y);
    o.z = f2bf(x2 * sc * wv.z); o.w = f2bf(x3 * sc * wv.w);
    *(ushort4*)&out[base] = o;
}

extern "C" void kernel_launch(void* const* d_in, const int* in_sizes, int n_in,
                              void* d_out, int out_size, void* d_ws, size_t ws_size,
                              hipStream_t stream) {
    const float* X      = (const float*)d_in[0];
    const float* Wq     = (const float*)d_in[1];
    const float* Wk     = (const float*)d_in[2];
    const float* Wv     = (const float*)d_in[3];
    const float* Wb     = (const float*)d_in[4];
    const float* conv_q = (const float*)d_in[5];
    const float* conv_k = (const float*)d_in[6];
    const float* conv_v = (const float*)d_in[7];
    const float* norm_w = (const float*)d_in[8];
    const float* Wo     = (const float*)d_in[9];
    float* out = (float*)d_out;

    char* W8 = (char*)d_ws;
    const size_t MB = 1u << 20;
    u16t* Xbf   = (u16t*)(W8 + 0 * MB);
    u16t* o_raw = Xbf;
    u16t* qpre  = (u16t*)(W8 + 8 * MB);
    u16t* o_nrm = qpre;
    u16t* kpre  = (u16t*)(W8 + 16 * MB);
    u16t* Tghi  = (u16t*)(W8 + 16 * MB);
    u16t* Tglo  = (u16t*)(W8 + 18 * MB);
    u16t* Agb   = (u16t*)(W8 + 20 * MB);
    u16t* vpre  = (u16t*)(W8 + 24 * MB);
    u16t* ktr   = (u16t*)(W8 + 24 * MB);
    u16t* WqT   = (u16t*)(W8 + 32 * MB);
    u16t* qcb   = (u16t*)(W8 + 32 * MB);
    u16t* WkT   = (u16t*)(W8 + 40 * MB);
    u16t* kcb   = (u16t*)(W8 + 40 * MB);
    u16t* WvT   = (u16t*)(W8 + 48 * MB);
    u16t* vcb   = (u16t*)(W8 + 48 * MB);
    u16t* WoT   = (u16t*)(W8 + 56 * MB);
    float* betab = (float*)(W8 + 58 * MB);

    const size_t PL = 4194304;   // 8 MB plane stride in u16 elements

    f2bf_kernel<<<2048, 256, 0, stream>>>(X, Xbf);
    transpose_w4<<<dim3(16, 16, 4), 256, 0, stream>>>(Wq, Wk, Wv, Wo, WqT, WkT, WvT, WoT);

    gemm_mfma<<<dim3(24, 32), 256, 0, stream>>>(Xbf, WqT, nullptr, qpre, 1,
                                                ROWS, 3072, HIDD, PL, PL);
    beta_kernel<<<ROWS / 4, 256, 0, stream>>>(X, Wb, betab);

    conv_qv<<<dim3(ROWS, 2), 256, 0, stream>>>(qpre, conv_q, qcb, vpre, conv_v, vcb);
    conv_k_chunk<<<256, 256, 0, stream>>>(kpre, conv_k, kcb, ktr);

    prep_kernel<<<256, 256, 0, stream>>>(qcb, kcb, betab, Tghi, Tglo, Agb);
    scan_mfma<<<128, 256, 0, stream>>>(qcb, kcb, ktr, vcb, betab, Tghi, Tglo, Agb, o_raw);

    rms_kernel<<<ROWS, 256, 0, stream>>>(o_raw, norm_w, o_nrm);
    gemm_mfma<<<dim3(8, 32), 256, 0, stream>>>(o_nrm, WoT, out, nullptr, 0,
                                               ROWS, HIDD, HIDD, 0, 0);
}